// Round 1
// baseline (555.372 us; speedup 1.0000x reference)
//
#include <hip/hip_runtime.h>

// SOAP energy: out = bias + sum_i c_i^T M c_i
// c layout per atom: c[i][m][a][n]  (m-major: 9 * 3 * 12 = 324 floats/atom)
// A layout: A[l][an][bk], an = a*12+n, bk = b*12+k, 36x36 per l, 3 l-blocks.

#define NMAX 12
#define NT 3
#define CPA 324          // floats per atom in c
#define A_ELEMS 3888     // 3*36*36

__global__ void prep_kernel(const float* __restrict__ w,
                            const float* __restrict__ bias,
                            float* __restrict__ A,
                            float* __restrict__ out) {
    int t = blockIdx.x * blockDim.x + threadIdx.x;
    if (t == 0) out[0] = bias[0];
    if (t < A_ELEMS) {
        int l   = t / 1296;
        int rem = t - l * 1296;
        int an  = rem / 36;
        int bk  = rem - an * 36;
        int a = an / 12, n = an - (an / 12) * 12;
        int b = bk / 12, k = bk - (bk / 12) * 12;
        float inv = (l == 0) ? 1.0f : (l == 1 ? 0.57735026918962576f
                                              : 0.44721359549995794f);
        // feats flat index: a*1296 + n*108 + b*36 + k*3 + l
        A[t] = w[a * 1296 + n * 108 + b * 36 + k * 3 + l] * inv;
    }
}

// One wave (64 lanes) per edge. Lane idx covers the 108 (m,n) products:
// idx = m*12 + n  ->  write address c[i*324 + m*36 + tj*12 + n]
__global__ void edge_kernel(const float* __restrict__ pos,
                            const int* __restrict__ types,
                            const int* __restrict__ pairs,
                            float* __restrict__ c, int E) {
    int gtid = blockIdx.x * blockDim.x + threadIdx.x;
    int e = gtid >> 6;
    int lane = threadIdx.x & 63;
    if (e >= E) return;

    int i = pairs[2 * e];
    int j = pairs[2 * e + 1];
    float dx = pos[3 * j + 0] - pos[3 * i + 0];
    float dy = pos[3 * j + 1] - pos[3 * i + 1];
    float dz = pos[3 * j + 2] - pos[3 * i + 2];
    float r2 = dx * dx + dy * dy + dz * dz + 1e-12f;
    float r  = sqrtf(r2);
    if (r >= 3.6f) return;   // cutoff = 0, whole wave exits

    float fc = (r < 3.3f) ? 1.0f
             : 0.5f * (1.0f + __cosf(10.471975511965978f * (r - 3.3f))); // pi/0.3

    float inv_r = 1.0f / r;
    float x = dx * inv_r, y = dy * inv_r, z = dz * inv_r;
    int tj = types[j];
    float* cb = c + (size_t)i * CPA + tj * 12;

    #pragma unroll
    for (int rep = 0; rep < 2; ++rep) {
        int idx = lane + rep * 64;
        if (idx < 108) {
            int m = idx / 12;
            int n = idx - m * 12;
            float sig = 0.3f * fmaxf(sqrtf((float)n), 1.0f);
            float q = r / sig;
            float Rn = __powf(r, (float)n) * __expf(-0.5f * q * q);
            float Ym;
            if      (m == 0) Ym = 0.28209479177387814f;
            else if (m == 1) Ym = 0.4886025119029199f * y;
            else if (m == 2) Ym = 0.4886025119029199f * z;
            else if (m == 3) Ym = 0.4886025119029199f * x;
            else if (m == 4) Ym = 1.0925484305920792f * x * y;
            else if (m == 5) Ym = 1.0925484305920792f * y * z;
            else if (m == 6) Ym = 0.31539156525252005f * (3.0f * z * z - 1.0f);
            else if (m == 7) Ym = 1.0925484305920792f * x * z;
            else             Ym = 0.5462742152960396f * (x * x - y * y);
            atomicAdd(cb + m * 36 + n, Rn * Ym * fc);
        }
    }
}

// Thread-per-atom quadratic form: dot_i = sum_m v_m^T A_{l(m)} v_m
__global__ void atom_kernel(const float* __restrict__ c,
                            const int* __restrict__ types,
                            const float* __restrict__ A,
                            float* __restrict__ out, int N) {
    __shared__ float sA[A_ELEMS];
    for (int t = threadIdx.x; t < A_ELEMS; t += blockDim.x) sA[t] = A[t];
    __syncthreads();

    int i = blockIdx.x * blockDim.x + threadIdx.x;
    float dot = 0.0f;
    if (i < N) {
        int ti = types[i];
        const float* cb = c + (size_t)i * CPA;
        for (int m = 0; m < 9; ++m) {
            float v[36];
            #pragma unroll
            for (int an = 0; an < 36; ++an) v[an] = cb[m * 36 + an];
            if (m == 0) {
                // c[i, type_i, n=0, m=0] += Y00  (an = ti*12, compile-time indexed)
                const float Y00 = 0.28209479177387814f;
                if      (ti == 0) v[0]  += Y00;
                else if (ti == 1) v[12] += Y00;
                else              v[24] += Y00;
            }
            int l = (m == 0) ? 0 : (m < 4 ? 1 : 2);
            const float* Al = sA + l * 1296;
            float acc = 0.0f;
            #pragma unroll
            for (int an = 0; an < 36; ++an) {
                float s = 0.0f;
                #pragma unroll
                for (int bk = 0; bk < 36; ++bk)
                    s = fmaf(Al[an * 36 + bk], v[bk], s);
                acc = fmaf(v[an], s, acc);
            }
            dot += acc;
        }
    }
    // wave reduce then one atomic per wave
    #pragma unroll
    for (int off = 32; off > 0; off >>= 1) dot += __shfl_down(dot, off, 64);
    if ((threadIdx.x & 63) == 0) atomicAdd(out, dot);
}

extern "C" void kernel_launch(void* const* d_in, const int* in_sizes, int n_in,
                              void* d_out, int out_size, void* d_ws, size_t ws_size,
                              hipStream_t stream) {
    const float* pos   = (const float*)d_in[0];
    const float* w     = (const float*)d_in[1];
    const float* bias  = (const float*)d_in[2];
    const int*   types = (const int*)d_in[3];
    const int*   pairs = (const int*)d_in[4];
    float* out = (float*)d_out;

    int N = in_sizes[0] / 3;
    int E = in_sizes[4] / 2;

    float* A = (float*)d_ws;                 // 3888 floats
    float* c = (float*)d_ws + 4096;          // 16 KiB offset, N*324 floats
    size_t c_bytes = (size_t)N * CPA * sizeof(float);

    hipMemsetAsync(c, 0, c_bytes, stream);
    prep_kernel<<<16, 256, 0, stream>>>(w, bias, A, out);

    int eblocks = (E + 3) / 4;               // 4 waves/block, 1 edge per wave
    edge_kernel<<<eblocks, 256, 0, stream>>>(pos, types, pairs, c, E);

    int ablocks = (N + 255) / 256;
    atom_kernel<<<ablocks, 256, 0, stream>>>(c, types, A, out, N);
}

// Round 2
// 304.196 us; speedup vs baseline: 1.8257x; 1.8257x over previous
//
#include <hip/hip_runtime.h>

// SOAP energy: out = bias + sum_i c_i^T M c_i
// c layout per atom: c[i][m][a][n]  (m-major: 9 * 3 * 12 = 324 floats/atom)
// A layout: A[l][an][bk], an = a*12+n, bk = b*12+k, 36x36 per l.

#define NMAX 12
#define NT 3
#define CPA 324
#define A_ELEMS 3888
#define SCAN_T 1024

__global__ void prep_kernel(const float* __restrict__ w,
                            const float* __restrict__ bias,
                            float* __restrict__ A,
                            float* __restrict__ out) {
    int t = blockIdx.x * blockDim.x + threadIdx.x;
    if (t == 0) out[0] = bias[0];
    if (t < A_ELEMS) {
        int l   = t / 1296;
        int rem = t - l * 1296;
        int an  = rem / 36;
        int bk  = rem - an * 36;
        int a = an / 12, n = an - (an / 12) * 12;
        int b = bk / 12, k = bk - (bk / 12) * 12;
        float inv = (l == 0) ? 1.0f : (l == 1 ? 0.57735026918962576f
                                              : 0.44721359549995794f);
        A[t] = w[a * 1296 + n * 108 + b * 36 + k * 3 + l] * inv;
    }
}

__device__ __forceinline__ float edge_r(const float* pos, int i, int j) {
    float dx = pos[3 * j + 0] - pos[3 * i + 0];
    float dy = pos[3 * j + 1] - pos[3 * i + 1];
    float dz = pos[3 * j + 2] - pos[3 * i + 2];
    return sqrtf(dx * dx + dy * dy + dz * dz + 1e-12f);
}

// Pass 1: per-atom degree histogram (filtered by cutoff)
__global__ void count_kernel(const float* __restrict__ pos,
                             const int* __restrict__ pairs,
                             int* __restrict__ cnt, int E) {
    int e = blockIdx.x * blockDim.x + threadIdx.x;
    if (e >= E) return;
    int i = pairs[2 * e], j = pairs[2 * e + 1];
    if (edge_r(pos, i, j) < 3.6f) atomicAdd(&cnt[i], 1);
}

// Single-block exclusive scan: cnt -> rowptr, and reset cursor=rowptr
__global__ void scan_kernel(int* __restrict__ cnt,     // in (destroyed)
                            int* __restrict__ rowptr,  // out, N+1
                            int N) {
    __shared__ int part[SCAN_T];
    int t = threadIdx.x;
    int chunk = (N + SCAN_T - 1) / SCAN_T;
    int s = 0;
    for (int k = 0; k < chunk; ++k) {
        int idx = t * chunk + k;
        if (idx < N) s += cnt[idx];
    }
    part[t] = s;
    __syncthreads();
    for (int off = 1; off < SCAN_T; off <<= 1) {
        int v = (t >= off) ? part[t - off] : 0;
        __syncthreads();
        part[t] += v;
        __syncthreads();
    }
    int run = part[t] - s;   // exclusive base for this thread's chunk
    for (int k = 0; k < chunk; ++k) {
        int idx = t * chunk + k;
        if (idx < N) {
            int cv = cnt[idx];
            rowptr[idx] = run;
            cnt[idx] = run;      // becomes scatter cursor
            run += cv;
        }
    }
    if (t == SCAN_T - 1) rowptr[N] = part[SCAN_T - 1];
}

// Pass 2: scatter j indices into buckets
__global__ void scatter_kernel(const float* __restrict__ pos,
                               const int* __restrict__ pairs,
                               int* __restrict__ cursor,
                               int* __restrict__ ebj, int E) {
    int e = blockIdx.x * blockDim.x + threadIdx.x;
    if (e >= E) return;
    int i = pairs[2 * e], j = pairs[2 * e + 1];
    if (edge_r(pos, i, j) < 3.6f) {
        int p = atomicAdd(&cursor[i], 1);
        ebj[p] = j;
    }
}

// One wave per atom: accumulate c[i][m][a][n] in registers, plain stores.
// Lane owns slots idx=lane and idx=lane+64 (idx<108), idx = m*12+n.
__global__ void accum_kernel(const float* __restrict__ pos,
                             const int* __restrict__ types,
                             const int* __restrict__ rowptr,
                             const int* __restrict__ ebj,
                             float* __restrict__ c, int N) {
    int wid = (blockIdx.x * blockDim.x + threadIdx.x) >> 6;
    int lane = threadIdx.x & 63;
    if (wid >= N) return;
    int i = wid;

    float xi = pos[3 * i + 0], yi = pos[3 * i + 1], zi = pos[3 * i + 2];
    int beg = rowptr[i], end = rowptr[i + 1];

    int idx0 = lane;          // always < 108
    int idx1 = lane + 64;
    bool has1 = idx1 < 108;
    int m0 = idx0 / 12, n0 = idx0 - m0 * 12;
    int m1 = idx1 / 12, n1 = idx1 - m1 * 12;
    float sg0 = 0.3f * fmaxf(sqrtf((float)n0), 1.0f);
    float sg1 = 0.3f * fmaxf(sqrtf((float)n1), 1.0f);
    float is0 = -0.5f / (sg0 * sg0);
    float is1 = -0.5f / (sg1 * sg1);
    float fn0 = (float)n0, fn1 = (float)n1;

    float a00 = 0.f, a01 = 0.f, a02 = 0.f;
    float a10 = 0.f, a11 = 0.f, a12 = 0.f;

    for (int e = beg; e < end; ++e) {
        int j = ebj[e];
        float dx = pos[3 * j + 0] - xi;
        float dy = pos[3 * j + 1] - yi;
        float dz = pos[3 * j + 2] - zi;
        int tj = types[j];
        float r2 = dx * dx + dy * dy + dz * dz + 1e-12f;
        float r = sqrtf(r2);
        float fc = (r < 3.3f) ? 1.0f
                 : 0.5f * (1.0f + __cosf(10.471975511965978f * (r - 3.3f)));
        float ir = 1.0f / r;
        float x = dx * ir, y = dy * ir, z = dz * ir;
        float lr = __logf(r);

        float Y0 = 0.28209479177387814f;
        float Y1 = 0.4886025119029199f * y;
        float Y2 = 0.4886025119029199f * z;
        float Y3 = 0.4886025119029199f * x;
        float Y4 = 1.0925484305920792f * x * y;
        float Y5 = 1.0925484305920792f * y * z;
        float Y6 = 0.31539156525252005f * (3.0f * z * z - 1.0f);
        float Y7 = 1.0925484305920792f * x * z;
        float Y8 = 0.5462742152960396f * (x * x - y * y);

        float Ym0 = m0 == 0 ? Y0 : m0 == 1 ? Y1 : m0 == 2 ? Y2 : m0 == 3 ? Y3
                  : m0 == 4 ? Y4 : m0 == 5 ? Y5 : m0 == 6 ? Y6 : m0 == 7 ? Y7 : Y8;
        float Ym1 = m1 == 0 ? Y0 : m1 == 1 ? Y1 : m1 == 2 ? Y2 : m1 == 3 ? Y3
                  : m1 == 4 ? Y4 : m1 == 5 ? Y5 : m1 == 6 ? Y6 : m1 == 7 ? Y7 : Y8;

        float v0 = __expf(fmaf(fn0, lr, is0 * r2)) * Ym0 * fc;
        a00 += (tj == 0) ? v0 : 0.f;
        a01 += (tj == 1) ? v0 : 0.f;
        a02 += (tj == 2) ? v0 : 0.f;
        if (has1) {
            float v1 = __expf(fmaf(fn1, lr, is1 * r2)) * Ym1 * fc;
            a10 += (tj == 0) ? v1 : 0.f;
            a11 += (tj == 1) ? v1 : 0.f;
            a12 += (tj == 2) ? v1 : 0.f;
        }
    }

    float* cb = c + (size_t)i * CPA;
    cb[m0 * 36 + 0 * 12 + n0] = a00;
    cb[m0 * 36 + 1 * 12 + n0] = a01;
    cb[m0 * 36 + 2 * 12 + n0] = a02;
    if (has1) {
        cb[m1 * 36 + 0 * 12 + n1] = a10;
        cb[m1 * 36 + 1 * 12 + n1] = a11;
        cb[m1 * 36 + 2 * 12 + n1] = a12;
    }
}

// Thread-per-atom quadratic form: dot_i = sum_m v_m^T A_{l(m)} v_m
__global__ void atom_kernel(const float* __restrict__ c,
                            const int* __restrict__ types,
                            const float* __restrict__ A,
                            float* __restrict__ out, int N) {
    __shared__ float sA[A_ELEMS];
    for (int t = threadIdx.x; t < A_ELEMS; t += blockDim.x) sA[t] = A[t];
    __syncthreads();

    int i = blockIdx.x * blockDim.x + threadIdx.x;
    float dot = 0.0f;
    if (i < N) {
        int ti = types[i];
        const float* cb = c + (size_t)i * CPA;
        for (int m = 0; m < 9; ++m) {
            float v[36];
            #pragma unroll
            for (int an = 0; an < 36; ++an) v[an] = cb[m * 36 + an];
            if (m == 0) {
                const float Y00 = 0.28209479177387814f;
                if      (ti == 0) v[0]  += Y00;
                else if (ti == 1) v[12] += Y00;
                else              v[24] += Y00;
            }
            int l = (m == 0) ? 0 : (m < 4 ? 1 : 2);
            const float* Al = sA + l * 1296;
            float acc = 0.0f;
            #pragma unroll
            for (int an = 0; an < 36; ++an) {
                float s = 0.0f;
                #pragma unroll
                for (int bk = 0; bk < 36; ++bk)
                    s = fmaf(Al[an * 36 + bk], v[bk], s);
                acc = fmaf(v[an], s, acc);
            }
            dot += acc;
        }
    }
    #pragma unroll
    for (int off = 32; off > 0; off >>= 1) dot += __shfl_down(dot, off, 64);
    if ((threadIdx.x & 63) == 0) atomicAdd(out, dot);
}

extern "C" void kernel_launch(void* const* d_in, const int* in_sizes, int n_in,
                              void* d_out, int out_size, void* d_ws, size_t ws_size,
                              hipStream_t stream) {
    const float* pos   = (const float*)d_in[0];
    const float* w     = (const float*)d_in[1];
    const float* bias  = (const float*)d_in[2];
    const int*   types = (const int*)d_in[3];
    const int*   pairs = (const int*)d_in[4];
    float* out = (float*)d_out;

    int N = in_sizes[0] / 3;
    int E = in_sizes[4] / 2;

    char* ws = (char*)d_ws;
    float* A     = (float*)ws;                           // 16 KB
    int*   rowptr= (int*)(ws + 16384);                   // 128 KB (N+1 ints)
    int*   cursor= (int*)(ws + 16384 + 131072);          // 128 KB (N ints)
    int*   ebj   = (int*)(ws + 16384 + 262144);          // E ints
    size_t ebytes = ((size_t)E * 4 + 255) & ~(size_t)255;
    float* c     = (float*)(ws + 16384 + 262144 + ebytes); // N*324 floats

    hipMemsetAsync(cursor, 0, (size_t)N * sizeof(int), stream);
    prep_kernel<<<16, 256, 0, stream>>>(w, bias, A, out);

    int eb = (E + 255) / 256;
    count_kernel<<<eb, 256, 0, stream>>>(pos, pairs, cursor, E);
    scan_kernel<<<1, SCAN_T, 0, stream>>>(cursor, rowptr, N);
    scatter_kernel<<<eb, 256, 0, stream>>>(pos, pairs, cursor, ebj, E);

    int ablocks = (N * 64 + 255) / 256;                  // one wave per atom
    accum_kernel<<<ablocks, 256, 0, stream>>>(pos, types, rowptr, ebj, c, N);

    int qblocks = (N + 255) / 256;
    atom_kernel<<<qblocks, 256, 0, stream>>>(c, types, A, out, N);
}

// Round 3
// 153.825 us; speedup vs baseline: 3.6104x; 1.9775x over previous
//
#include <hip/hip_runtime.h>
#include <hip/hip_bf16.h>

// out = bias + sum_i sum_m v_{i,m}^T A_{l(m)} v_{i,m}
// c2 layout: c2[atom][slot], slot = m*36 + a*12 + n  (bf16, 324/atom)
// A layout: A[l][an][bk], an=a*12+n, 36x36 per l.

#define NT 3
#define CPA 324
#define A_ELEMS 3888
#define BCAP 64

__global__ void prep_kernel(const float* __restrict__ w,
                            const float* __restrict__ bias,
                            const float* __restrict__ pos,
                            const int* __restrict__ types,
                            float* __restrict__ A,
                            float4* __restrict__ posT,
                            float* __restrict__ out, int N) {
    int t = blockIdx.x * blockDim.x + threadIdx.x;
    if (t == 0) out[0] = bias[0];
    if (t < A_ELEMS) {
        int l   = t / 1296;
        int rem = t - l * 1296;
        int an  = rem / 36;
        int bk  = rem - an * 36;
        int a = an / 12, n = an - (an / 12) * 12;
        int b = bk / 12, k = bk - (bk / 12) * 12;
        float inv = (l == 0) ? 1.0f : (l == 1 ? 0.57735026918962576f
                                              : 0.44721359549995794f);
        A[t] = w[a * 1296 + n * 108 + b * 36 + k * 3 + l] * inv;
    }
    if (t < N) {
        float4 p;
        p.x = pos[3 * t + 0];
        p.y = pos[3 * t + 1];
        p.z = pos[3 * t + 2];
        p.w = __int_as_float(types[t]);
        posT[t] = p;
    }
}

// Single filtering pass into fixed-capacity buckets (no scan, no CSR).
__global__ void build_kernel(const int2* __restrict__ pairs,
                             const float4* __restrict__ posT,
                             int* __restrict__ cnt,
                             int* __restrict__ bucket, int E) {
    int e = blockIdx.x * blockDim.x + threadIdx.x;
    if (e >= E) return;
    int2 pr = pairs[e];
    float4 pi = posT[pr.x], pj = posT[pr.y];
    float dx = pj.x - pi.x, dy = pj.y - pi.y, dz = pj.z - pi.z;
    float r2 = dx * dx + dy * dy + dz * dz;
    if (r2 < 12.96f) {
        int p = atomicAdd(&cnt[pr.x], 1);
        if (p < BCAP) bucket[(pr.x << 6) + p] = pr.y;
    }
}

// One wave per atom. Edge scalars are wave-uniform -> scalar loads.
// Lane owns slots idx0=lane, idx1=lane+64 (idx=m*12+n, idx<108).
__global__ void __launch_bounds__(256)
accum_kernel(const float4* __restrict__ posT,
             const int* __restrict__ cnt,
             const int* __restrict__ bucket,
             __hip_bfloat16* __restrict__ c2, int N) {
    int wid = (blockIdx.x * blockDim.x + threadIdx.x) >> 6;
    int lane = threadIdx.x & 63;
    if (wid >= N) return;
    int i = wid;

    float4 pi = posT[i];
    int deg = cnt[i];
    deg = deg > BCAP ? BCAP : deg;
    const int* bkt = bucket + (i << 6);

    int n0 = lane % 12, m0 = lane / 12;
    int idx1 = lane + 64;
    bool has1 = idx1 < 108;
    int m1 = has1 ? idx1 / 12 : 0;
    int n1 = idx1 - (idx1 / 12) * 12;

    float fn0 = (float)n0;
    float sg0 = 0.3f * fmaxf(sqrtf(fn0), 1.0f);
    float qc0 = -0.5f / (sg0 * sg0);
    int bpa = ((lane + 4) % 12) << 2;   // bpermute byte addr: source lane holds rad for n1

    // Ym = K * sel(ca)*sel(cb) + C ; codes: 0:1 1:x 2:y 3:z 4:x+y 5:x-y
    int ca0 = (0x42D12D0 >> (3 * m0)) & 7;
    int cb0 = (0x56DA000 >> (3 * m0)) & 7;
    int ca1 = (0x42D12D0 >> (3 * m1)) & 7;
    int cb1 = (0x56DA000 >> (3 * m1)) & 7;
    float K0 = m0 == 0 ? 0.28209479177387814f
             : (m0 < 4 ? 0.4886025119029199f
             : (m0 == 6 ? 0.94617469575756f
             : (m0 == 8 ? 0.5462742152960396f : 1.0925484305920792f)));
    float C0 = m0 == 6 ? -0.31539156525252005f : 0.0f;
    float K1 = m1 == 0 ? 0.28209479177387814f
             : (m1 < 4 ? 0.4886025119029199f
             : (m1 == 6 ? 0.94617469575756f
             : (m1 == 8 ? 0.5462742152960396f : 1.0925484305920792f)));
    float C1 = m1 == 6 ? -0.31539156525252005f : 0.0f;
    if (!has1) { K1 = 0.0f; C1 = 0.0f; }

    float a00 = 0.f, a01 = 0.f, a02 = 0.f;
    float a10 = 0.f, a11 = 0.f, a12 = 0.f;

    for (int e = 0; e < deg; ++e) {
        int j = __builtin_amdgcn_readfirstlane(bkt[e]);
        float4 pj = posT[j];
        int tj = __float_as_int(pj.w);
        float dx = pj.x - pi.x, dy = pj.y - pi.y, dz = pj.z - pi.z;
        float r2 = fmaf(dz, dz, fmaf(dy, dy, fmaf(dx, dx, 1e-12f)));
        float lr = 0.5f * __logf(r2);          // ln r
        float ir = rsqrtf(r2);
        float x = dx * ir, y = dy * ir, z = dz * ir;
        float xpy = x + y, xmy = x - y;

        float t0 = tj == 0 ? 1.f : 0.f;
        float t1 = tj == 1 ? 1.f : 0.f;
        float t2 = tj == 2 ? 1.f : 0.f;
        if (r2 >= 10.89f) {                    // r >= 3.3 : taper (13% of edges)
            float r = r2 * ir;
            float fcv = 0.5f * (1.0f + __cosf(10.471975511965978f * (r - 3.3f)));
            t0 *= fcv; t1 *= fcv; t2 *= fcv;
        }

        float rad0 = __expf(fmaf(fn0, lr, qc0 * r2));
        float rad1 = __int_as_float(
            __builtin_amdgcn_ds_bpermute(bpa, __float_as_int(rad0)));

        float pa0 = 1.0f;
        pa0 = ca0 == 1 ? x : pa0; pa0 = ca0 == 2 ? y : pa0;
        pa0 = ca0 == 3 ? z : pa0; pa0 = ca0 == 4 ? xpy : pa0;
        pa0 = ca0 == 5 ? xmy : pa0;
        float pb0 = 1.0f;
        pb0 = cb0 == 1 ? x : pb0; pb0 = cb0 == 2 ? y : pb0;
        pb0 = cb0 == 3 ? z : pb0; pb0 = cb0 == 4 ? xpy : pb0;
        pb0 = cb0 == 5 ? xmy : pb0;
        float v0 = rad0 * fmaf(pa0 * pb0, K0, C0);
        a00 = fmaf(v0, t0, a00); a01 = fmaf(v0, t1, a01); a02 = fmaf(v0, t2, a02);

        float pa1 = 1.0f;
        pa1 = ca1 == 1 ? x : pa1; pa1 = ca1 == 2 ? y : pa1;
        pa1 = ca1 == 3 ? z : pa1; pa1 = ca1 == 4 ? xpy : pa1;
        pa1 = ca1 == 5 ? xmy : pa1;
        float pb1 = 1.0f;
        pb1 = cb1 == 1 ? x : pb1; pb1 = cb1 == 2 ? y : pb1;
        pb1 = cb1 == 3 ? z : pb1; pb1 = cb1 == 4 ? xpy : pb1;
        pb1 = cb1 == 5 ? xmy : pb1;
        float v1 = rad1 * fmaf(pa1 * pb1, K1, C1);
        a10 = fmaf(v1, t0, a10); a11 = fmaf(v1, t1, a11); a12 = fmaf(v1, t2, a12);
    }

    __hip_bfloat16* cb = c2 + (size_t)i * CPA;
    cb[m0 * 36 + 0 * 12 + n0] = __float2bfloat16(a00);
    cb[m0 * 36 + 1 * 12 + n0] = __float2bfloat16(a01);
    cb[m0 * 36 + 2 * 12 + n0] = __float2bfloat16(a02);
    if (has1) {
        cb[m1 * 36 + 0 * 12 + n1] = __float2bfloat16(a10);
        cb[m1 * 36 + 1 * 12 + n1] = __float2bfloat16(a11);
        cb[m1 * 36 + 2 * 12 + n1] = __float2bfloat16(a12);
    }
}

// Wave = (64 atoms, one m). A reads wave-uniform -> scalar loads from global.
__global__ void __launch_bounds__(576)
quad_kernel(const __hip_bfloat16* __restrict__ c2,
            const int* __restrict__ types,
            const float* __restrict__ A,
            float* __restrict__ out, int N) {
    __shared__ float sred[9];
    int m = __builtin_amdgcn_readfirstlane(threadIdx.x >> 6);
    int lane = threadIdx.x & 63;
    int i = blockIdx.x * 64 + lane;
    float dot = 0.0f;
    if (i < N) {
        const __hip_bfloat16* cb = c2 + (size_t)i * CPA + m * 36;
        float v[36];
        #pragma unroll
        for (int an = 0; an < 36; ++an) v[an] = __bfloat162float(cb[an]);
        if (m == 0) {
            int ti = types[i];
            const float Y00 = 0.28209479177387814f;
            v[0]  += ti == 0 ? Y00 : 0.f;
            v[12] += ti == 1 ? Y00 : 0.f;
            v[24] += ti == 2 ? Y00 : 0.f;
        }
        int l = (m == 0) ? 0 : (m < 4 ? 1 : 2);
        const float* Al = A + l * 1296;
        #pragma unroll
        for (int an = 0; an < 36; ++an) {
            float s = 0.0f;
            #pragma unroll
            for (int b = 0; b < 36; ++b)
                s = fmaf(Al[an * 36 + b], v[b], s);
            dot = fmaf(v[an], s, dot);
        }
    }
    #pragma unroll
    for (int off = 32; off > 0; off >>= 1) dot += __shfl_down(dot, off, 64);
    if (lane == 0) sred[m] = dot;
    __syncthreads();
    if (threadIdx.x == 0) {
        float s = 0.f;
        #pragma unroll
        for (int k = 0; k < 9; ++k) s += sred[k];
        atomicAdd(out, s);
    }
}

extern "C" void kernel_launch(void* const* d_in, const int* in_sizes, int n_in,
                              void* d_out, int out_size, void* d_ws, size_t ws_size,
                              hipStream_t stream) {
    const float* pos   = (const float*)d_in[0];
    const float* w     = (const float*)d_in[1];
    const float* bias  = (const float*)d_in[2];
    const int*   types = (const int*)d_in[3];
    const int*   pairs = (const int*)d_in[4];
    float* out = (float*)d_out;

    int N = in_sizes[0] / 3;
    int E = in_sizes[4] / 2;

    char* ws = (char*)d_ws;
    size_t off = 0;
    float* A = (float*)(ws + off);            off += 16384;
    int* cnt = (int*)(ws + off);              off += ((size_t)N * 4 + 255) & ~(size_t)255;
    float4* posT = (float4*)(ws + off);       off += ((size_t)N * 16 + 255) & ~(size_t)255;
    int* bucket = (int*)(ws + off);           off += ((size_t)N * BCAP * 4 + 255) & ~(size_t)255;
    __hip_bfloat16* c2 = (__hip_bfloat16*)(ws + off);

    hipMemsetAsync(cnt, 0, (size_t)N * sizeof(int), stream);

    int pblocks = (N + 255) / 256;
    prep_kernel<<<pblocks, 256, 0, stream>>>(w, bias, pos, types, A, posT, out, N);

    int eblocks = (E + 255) / 256;
    build_kernel<<<eblocks, 256, 0, stream>>>((const int2*)pairs, posT, cnt, bucket, E);

    int ablocks = ((size_t)N * 64 + 255) / 256;
    accum_kernel<<<ablocks, 256, 0, stream>>>(posT, cnt, bucket, c2, N);

    int qblocks = (N + 63) / 64;
    quad_kernel<<<qblocks, 576, 0, stream>>>(c2, types, A, out, N);
}

// Round 4
// 144.992 us; speedup vs baseline: 3.8304x; 1.0609x over previous
//
#include <hip/hip_runtime.h>
#include <hip/hip_bf16.h>

// out = bias + sum_i sum_m K_m^2-scaled quadratic forms.
// accum stores UNSCALED c' (no K_m): c'[slot] = sum_edges poly_m(d)*r^(n-k)*gauss*fc
// quad rescales v = K_m * c' and adds Y00 self-term, then v^T A_l v.
// c2 layout: c2[atom][slot], slot = m*36 + a*12 + n  (bf16, 324/atom)

#define NT 3
#define CPA 324
#define A_ELEMS 3888
#define BCAP 64

typedef __attribute__((ext_vector_type(4))) unsigned short ushort4v;

__global__ void prep_kernel(const float* __restrict__ w,
                            const float* __restrict__ bias,
                            const float* __restrict__ pos,
                            const int* __restrict__ types,
                            float* __restrict__ A,
                            float4* __restrict__ posT,
                            int* __restrict__ cnt,
                            float* __restrict__ out, int N) {
    int t = blockIdx.x * blockDim.x + threadIdx.x;
    if (t == 0) out[0] = bias[0];
    if (t < A_ELEMS) {
        int l   = t / 1296;
        int rem = t - l * 1296;
        int an  = rem / 36;
        int bk  = rem - an * 36;
        int a = an / 12, n = an - (an / 12) * 12;
        int b = bk / 12, k = bk - (bk / 12) * 12;
        float inv = (l == 0) ? 1.0f : (l == 1 ? 0.57735026918962576f
                                              : 0.44721359549995794f);
        A[t] = w[a * 1296 + n * 108 + b * 36 + k * 3 + l] * inv;
    }
    if (t < N) {
        float4 p;
        p.x = pos[3 * t + 0];
        p.y = pos[3 * t + 1];
        p.z = pos[3 * t + 2];
        p.w = __int_as_float(types[t]);
        posT[t] = p;
        cnt[t] = 0;
    }
}

// Single filtering pass into fixed-capacity buckets.
__global__ void build_kernel(const int2* __restrict__ pairs,
                             const float4* __restrict__ posT,
                             int* __restrict__ cnt,
                             int* __restrict__ bucket, int E) {
    int e = blockIdx.x * blockDim.x + threadIdx.x;
    if (e >= E) return;
    int2 pr = pairs[e];
    float4 pi = posT[pr.x], pj = posT[pr.y];
    float dx = pj.x - pi.x, dy = pj.y - pi.y, dz = pj.z - pi.z;
    float r2 = dx * dx + dy * dy + dz * dz;
    if (r2 < 12.96f) {
        int p = atomicAdd(&cnt[pr.x], 1);
        if (p < BCAP) bucket[(pr.x << 6) + p] = pr.y;
    }
}

// Per-slot loop-invariant parameters (d-space polynomial coefficients).
struct Slot {
    float fnp, qc;                       // radial: exp(fnp*ln(r2) + qc*r2)
    float cxa, cya, cza, cca;            // pa = cxa*dx+cya*dy+cza*dz+cca
    float cxb, cyb, czb, ccb;            // pb
    float cc2;                           // t = pa*pb + cc2*r2
};

__device__ __forceinline__ void slot_init(int m, int n, Slot& s) {
    float fn = (float)n;
    float sg = 0.3f * fmaxf(sqrtf(fn), 1.0f);
    s.qc  = -0.5f / (sg * sg);
    int k = (m == 0) ? 0 : (m < 4 ? 1 : 2);
    s.fnp = 0.5f * (fn - (float)k);
    s.cxa = (m == 3 || m == 4 || m == 7 || m == 8) ? 1.f : 0.f;
    s.cya = (m == 1 || m == 5) ? 1.f : (m == 8 ? -1.f : 0.f);
    s.cza = (m == 2 || m == 6) ? 1.f : 0.f;
    s.cca = (m == 0) ? 1.f : 0.f;
    s.cxb = (m == 8) ? 1.f : 0.f;
    s.cyb = (m == 4 || m == 8) ? 1.f : 0.f;
    s.czb = (m == 5 || m == 6 || m == 7) ? 1.f : 0.f;
    s.ccb = (m <= 3) ? 1.f : 0.f;
    s.cc2 = (m == 6) ? -0.33333333333333333f : 0.f;
}

// One wave per atom; lane owns slots lane and lane+64 (slot = m*12+n < 108).
__global__ void __launch_bounds__(256)
accum_kernel(const float4* __restrict__ posT,
             const int* __restrict__ cnt,
             const int* __restrict__ bucket,
             __hip_bfloat16* __restrict__ c2, int N) {
    int wid = (blockIdx.x * blockDim.x + threadIdx.x) >> 6;
    int lane = threadIdx.x & 63;
    if (wid >= N) return;
    int i = wid;

    float4 pi = posT[i];
    int deg = cnt[i];
    deg = deg > BCAP ? BCAP : deg;
    const int* bkt = bucket + (i << 6);

    int n0 = lane % 12, m0 = lane / 12;
    int idx1 = lane + 64;
    bool has1 = idx1 < 108;
    int i1 = has1 ? idx1 : 0;
    int n1 = i1 % 12, m1 = i1 / 12;

    Slot s0, s1;
    slot_init(m0, n0, s0);
    slot_init(m1, n1, s1);

    float a00 = 0.f, a01 = 0.f, a02 = 0.f;
    float a10 = 0.f, a11 = 0.f, a12 = 0.f;

    if (deg > 0) {
        int jn = __builtin_amdgcn_readfirstlane(bkt[0]);
        float4 pj = posT[jn];
        for (int e = 0; e < deg; ++e) {
            float4 pc = pj;
            if (e + 1 < deg) {
                int j2 = __builtin_amdgcn_readfirstlane(bkt[e + 1]);
                pj = posT[j2];
            }
            int tj = __float_as_int(pc.w);
            float dx = pc.x - pi.x, dy = pc.y - pi.y, dz = pc.z - pi.z;
            float r2 = fmaf(dz, dz, fmaf(dy, dy, fmaf(dx, dx, 1e-12f)));
            float lr2 = __logf(r2);

            float rad0 = __expf(fmaf(s0.fnp, lr2, s0.qc * r2));
            float rad1 = __expf(fmaf(s1.fnp, lr2, s1.qc * r2));
            if (r2 >= 10.89f) {              // r >= 3.3: taper (uniform branch)
                float r = sqrtf(r2);
                float fcv = 0.5f + 0.5f * __cosf(10.471975511965978f * (r - 3.3f));
                rad0 *= fcv;
                rad1 *= fcv;
            }

            float pa0 = fmaf(s0.cxa, dx, fmaf(s0.cya, dy, fmaf(s0.cza, dz, s0.cca)));
            float pb0 = fmaf(s0.cxb, dx, fmaf(s0.cyb, dy, fmaf(s0.czb, dz, s0.ccb)));
            float v0  = rad0 * fmaf(pa0, pb0, s0.cc2 * r2);
            float pa1 = fmaf(s1.cxa, dx, fmaf(s1.cya, dy, fmaf(s1.cza, dz, s1.cca)));
            float pb1 = fmaf(s1.cxb, dx, fmaf(s1.cyb, dy, fmaf(s1.czb, dz, s1.ccb)));
            float v1  = rad1 * fmaf(pa1, pb1, s1.cc2 * r2);

            if (tj == 0)      { a00 += v0; a10 += v1; }
            else if (tj == 1) { a01 += v0; a11 += v1; }
            else              { a02 += v0; a12 += v1; }
        }
    }

    __hip_bfloat16* cb = c2 + (size_t)i * CPA;
    cb[m0 * 36 + 0 * 12 + n0] = __float2bfloat16(a00);
    cb[m0 * 36 + 1 * 12 + n0] = __float2bfloat16(a01);
    cb[m0 * 36 + 2 * 12 + n0] = __float2bfloat16(a02);
    if (has1) {
        cb[m1 * 36 + 0 * 12 + n1] = __float2bfloat16(a10);
        cb[m1 * 36 + 1 * 12 + n1] = __float2bfloat16(a11);
        cb[m1 * 36 + 2 * 12 + n1] = __float2bfloat16(a12);
    }
}

// Wave = (64 atoms, one m). Rescale v by K_m, add Y00 self-term, v^T A_l v.
__global__ void __launch_bounds__(576)
quad_kernel(const __hip_bfloat16* __restrict__ c2,
            const int* __restrict__ types,
            const float* __restrict__ A,
            float* __restrict__ out, int N) {
    __shared__ float sred[9];
    int m = __builtin_amdgcn_readfirstlane(threadIdx.x >> 6);
    int lane = threadIdx.x & 63;
    int i = blockIdx.x * 64 + lane;
    float dot = 0.0f;
    if (i < N) {
        float Km = m == 0 ? 0.28209479177387814f
                 : (m < 4 ? 0.4886025119029199f
                 : (m == 6 ? 0.94617469575756f
                 : (m == 8 ? 0.5462742152960396f : 1.0925484305920792f)));
        const ushort4v* cb4 =
            (const ushort4v*)(c2 + (size_t)i * CPA + m * 36);
        float v[36];
        #pragma unroll
        for (int q = 0; q < 9; ++q) {
            ushort4v u = cb4[q];
            #pragma unroll
            for (int r = 0; r < 4; ++r)
                v[q * 4 + r] = __uint_as_float(((unsigned)u[r]) << 16) * Km;
        }
        if (m == 0) {
            int ti = types[i];
            const float Y00 = 0.28209479177387814f;
            v[0]  += ti == 0 ? Y00 : 0.f;
            v[12] += ti == 1 ? Y00 : 0.f;
            v[24] += ti == 2 ? Y00 : 0.f;
        }
        int l = (m == 0) ? 0 : (m < 4 ? 1 : 2);
        const float* Al = A + l * 1296;
        #pragma unroll
        for (int an = 0; an < 36; ++an) {
            float s = 0.0f;
            #pragma unroll
            for (int b = 0; b < 36; ++b)
                s = fmaf(Al[an * 36 + b], v[b], s);
            dot = fmaf(v[an], s, dot);
        }
    }
    #pragma unroll
    for (int off = 32; off > 0; off >>= 1) dot += __shfl_down(dot, off, 64);
    if (lane == 0) sred[m] = dot;
    __syncthreads();
    if (threadIdx.x == 0) {
        float s = 0.f;
        #pragma unroll
        for (int k = 0; k < 9; ++k) s += sred[k];
        atomicAdd(out, s);
    }
}

extern "C" void kernel_launch(void* const* d_in, const int* in_sizes, int n_in,
                              void* d_out, int out_size, void* d_ws, size_t ws_size,
                              hipStream_t stream) {
    const float* pos   = (const float*)d_in[0];
    const float* w     = (const float*)d_in[1];
    const float* bias  = (const float*)d_in[2];
    const int*   types = (const int*)d_in[3];
    const int*   pairs = (const int*)d_in[4];
    float* out = (float*)d_out;

    int N = in_sizes[0] / 3;
    int E = in_sizes[4] / 2;

    char* ws = (char*)d_ws;
    size_t off = 0;
    float* A = (float*)(ws + off);            off += 16384;
    int* cnt = (int*)(ws + off);              off += ((size_t)N * 4 + 255) & ~(size_t)255;
    float4* posT = (float4*)(ws + off);       off += ((size_t)N * 16 + 255) & ~(size_t)255;
    int* bucket = (int*)(ws + off);           off += ((size_t)N * BCAP * 4 + 255) & ~(size_t)255;
    __hip_bfloat16* c2 = (__hip_bfloat16*)(ws + off);

    int pblocks = (N + 255) / 256;
    prep_kernel<<<pblocks, 256, 0, stream>>>(w, bias, pos, types, A, posT, cnt, out, N);

    int eblocks = (E + 255) / 256;
    build_kernel<<<eblocks, 256, 0, stream>>>((const int2*)pairs, posT, cnt, bucket, E);

    int ablocks = ((size_t)N * 64 + 255) / 256;
    accum_kernel<<<ablocks, 256, 0, stream>>>(posT, cnt, bucket, c2, N);

    int qblocks = (N + 63) / 64;
    quad_kernel<<<qblocks, 576, 0, stream>>>(c2, types, A, out, N);
}

// Round 5
// 141.272 us; speedup vs baseline: 3.9312x; 1.0263x over previous
//
#include <hip/hip_runtime.h>
#include <hip/hip_bf16.h>

// out = bias + sum_i sum_m quadratic forms (K_m folded into quad stage).
// accum stores UNSCALED c': c'[slot] = sum_edges poly_m(d)*r^(n-k)*gauss*fc
// c2 layout: c2[atom][slot], slot = m*36 + a*12 + n  (bf16, 324/atom)

#define NT 3
#define CPA 324
#define A_ELEMS 3888
#define BCAP 64

typedef __attribute__((ext_vector_type(4))) unsigned short ushort4v;

__global__ void prep_kernel(const float* __restrict__ w,
                            const float* __restrict__ bias,
                            const float* __restrict__ pos,
                            const int* __restrict__ types,
                            float* __restrict__ A,
                            float4* __restrict__ posT,
                            int* __restrict__ cnt,
                            float* __restrict__ out, int N) {
    int t = blockIdx.x * blockDim.x + threadIdx.x;
    if (t == 0) out[0] = bias[0];
    if (t < A_ELEMS) {
        int l   = t / 1296;
        int rem = t - l * 1296;
        int an  = rem / 36;
        int bk  = rem - an * 36;
        int a = an / 12, n = an - (an / 12) * 12;
        int b = bk / 12, k = bk - (bk / 12) * 12;
        float inv = (l == 0) ? 1.0f : (l == 1 ? 0.57735026918962576f
                                              : 0.44721359549995794f);
        A[t] = w[a * 1296 + n * 108 + b * 36 + k * 3 + l] * inv;
    }
    if (t < N) {
        float4 p;
        p.x = pos[3 * t + 0];
        p.y = pos[3 * t + 1];
        p.z = pos[3 * t + 2];
        p.w = __int_as_float(types[t]);
        posT[t] = p;
        cnt[t] = 0;
    }
}

// Single filtering pass into fixed-capacity buckets.
__global__ void build_kernel(const int2* __restrict__ pairs,
                             const float4* __restrict__ posT,
                             int* __restrict__ cnt,
                             int* __restrict__ bucket, int E) {
    int e = blockIdx.x * blockDim.x + threadIdx.x;
    if (e >= E) return;
    int2 pr = pairs[e];
    float4 pi = posT[pr.x], pj = posT[pr.y];
    float dx = pj.x - pi.x, dy = pj.y - pi.y, dz = pj.z - pi.z;
    float r2 = dx * dx + dy * dy + dz * dz;
    if (r2 < 12.96f) {
        int p = atomicAdd(&cnt[pr.x], 1);
        if (p < BCAP) bucket[(pr.x << 6) + p] = pr.y;
    }
}

// Per-slot loop-invariant parameters (d-space polynomial coefficients).
struct Slot {
    float fnp, qc;                       // radial: exp(fnp*ln(r2) + qc*r2)
    float cxa, cya, cza, cca;            // pa = cxa*dx+cya*dy+cza*dz+cca
    float cxb, cyb, czb, ccb;            // pb
    float cc2;                           // t = pa*pb + cc2*r2
};

__device__ __forceinline__ void slot_init(int m, int n, Slot& s) {
    float fn = (float)n;
    float sg = 0.3f * fmaxf(sqrtf(fn), 1.0f);
    s.qc  = -0.5f / (sg * sg);
    int k = (m == 0) ? 0 : (m < 4 ? 1 : 2);
    s.fnp = 0.5f * (fn - (float)k);
    s.cxa = (m == 3 || m == 4 || m == 7 || m == 8) ? 1.f : 0.f;
    s.cya = (m == 1 || m == 5) ? 1.f : (m == 8 ? -1.f : 0.f);
    s.cza = (m == 2 || m == 6) ? 1.f : 0.f;
    s.cca = (m == 0) ? 1.f : 0.f;
    s.cxb = (m == 8) ? 1.f : 0.f;
    s.cyb = (m == 4 || m == 8) ? 1.f : 0.f;
    s.czb = (m == 5 || m == 6 || m == 7) ? 1.f : 0.f;
    s.ccb = (m <= 3) ? 1.f : 0.f;
    s.cc2 = (m == 6) ? -0.33333333333333333f : 0.f;
}

// One wave per atom; lane owns slots lane and lane+64 (slot = m*12+n < 108).
// Bucket row loaded ONCE (coalesced, 64 lanes); j extracted via v_readlane;
// posT loads software-pipelined 2 deep with uniform addresses.
__global__ void __launch_bounds__(256)
accum_kernel(const float4* __restrict__ posT,
             const int* __restrict__ cnt,
             const int* __restrict__ bucket,
             __hip_bfloat16* __restrict__ c2, int N) {
    int wid = (blockIdx.x * blockDim.x + threadIdx.x) >> 6;
    int lane = threadIdx.x & 63;
    if (wid >= N) return;
    int i = wid;

    float4 pi = posT[i];
    int deg = cnt[i];
    deg = deg > BCAP ? BCAP : deg;
    int jv = bucket[(i << 6) + lane];       // whole bucket row, one load

    int n0 = lane % 12, m0 = lane / 12;
    int idx1 = lane + 64;
    bool has1 = idx1 < 108;
    int i1 = has1 ? idx1 : 0;
    int n1 = i1 % 12, m1 = i1 / 12;

    Slot s0, s1;
    slot_init(m0, n0, s0);
    slot_init(m1, n1, s1);

    float a00 = 0.f, a01 = 0.f, a02 = 0.f;
    float a10 = 0.f, a11 = 0.f, a12 = 0.f;

    if (deg > 0) {
        float4 pA, pB;
        {
            int j = __builtin_amdgcn_readlane(jv, 0);
            pA = posT[j];
        }
        if (deg > 1) {
            int j = __builtin_amdgcn_readlane(jv, 1);
            pB = posT[j];
        }
        for (int e = 0; e < deg; ++e) {
            float4 pc = pA;
            pA = pB;
            if (e + 2 < deg) {
                int j = __builtin_amdgcn_readlane(jv, e + 2);
                pB = posT[j];
            }
            int tj = __float_as_int(pc.w);
            float dx = pc.x - pi.x, dy = pc.y - pi.y, dz = pc.z - pi.z;
            float r2 = fmaf(dz, dz, fmaf(dy, dy, fmaf(dx, dx, 1e-12f)));
            float lr2 = __logf(r2);

            float rad0 = __expf(fmaf(s0.fnp, lr2, s0.qc * r2));
            float rad1 = __expf(fmaf(s1.fnp, lr2, s1.qc * r2));
            if (r2 >= 10.89f) {              // r >= 3.3: taper (uniform branch)
                float r = sqrtf(r2);
                float fcv = 0.5f + 0.5f * __cosf(10.471975511965978f * (r - 3.3f));
                rad0 *= fcv;
                rad1 *= fcv;
            }

            float pa0 = fmaf(s0.cxa, dx, fmaf(s0.cya, dy, fmaf(s0.cza, dz, s0.cca)));
            float pb0 = fmaf(s0.cxb, dx, fmaf(s0.cyb, dy, fmaf(s0.czb, dz, s0.ccb)));
            float v0  = rad0 * fmaf(pa0, pb0, s0.cc2 * r2);
            float pa1 = fmaf(s1.cxa, dx, fmaf(s1.cya, dy, fmaf(s1.cza, dz, s1.cca)));
            float pb1 = fmaf(s1.cxb, dx, fmaf(s1.cyb, dy, fmaf(s1.czb, dz, s1.ccb)));
            float v1  = rad1 * fmaf(pa1, pb1, s1.cc2 * r2);

            if (tj == 0)      { a00 += v0; a10 += v1; }
            else if (tj == 1) { a01 += v0; a11 += v1; }
            else              { a02 += v0; a12 += v1; }
        }
    }

    __hip_bfloat16* cb = c2 + (size_t)i * CPA;
    cb[m0 * 36 + 0 * 12 + n0] = __float2bfloat16(a00);
    cb[m0 * 36 + 1 * 12 + n0] = __float2bfloat16(a01);
    cb[m0 * 36 + 2 * 12 + n0] = __float2bfloat16(a02);
    if (has1) {
        cb[m1 * 36 + 0 * 12 + n1] = __float2bfloat16(a10);
        cb[m1 * 36 + 1 * 12 + n1] = __float2bfloat16(a11);
        cb[m1 * 36 + 2 * 12 + n1] = __float2bfloat16(a12);
    }
}

// Wave = (64 atoms, one m). Rescale v by K_m, add Y00 self-term, v^T A_l v.
__global__ void __launch_bounds__(576)
quad_kernel(const __hip_bfloat16* __restrict__ c2,
            const int* __restrict__ types,
            const float* __restrict__ A,
            float* __restrict__ out, int N) {
    __shared__ float sred[9];
    int m = __builtin_amdgcn_readfirstlane(threadIdx.x >> 6);
    int lane = threadIdx.x & 63;
    int i = blockIdx.x * 64 + lane;
    float dot = 0.0f;
    if (i < N) {
        float Km = m == 0 ? 0.28209479177387814f
                 : (m < 4 ? 0.4886025119029199f
                 : (m == 6 ? 0.94617469575756f
                 : (m == 8 ? 0.5462742152960396f : 1.0925484305920792f)));
        const ushort4v* cb4 =
            (const ushort4v*)(c2 + (size_t)i * CPA + m * 36);
        float v[36];
        #pragma unroll
        for (int q = 0; q < 9; ++q) {
            ushort4v u = cb4[q];
            #pragma unroll
            for (int r = 0; r < 4; ++r)
                v[q * 4 + r] = __uint_as_float(((unsigned)u[r]) << 16) * Km;
        }
        if (m == 0) {
            int ti = types[i];
            const float Y00 = 0.28209479177387814f;
            v[0]  += ti == 0 ? Y00 : 0.f;
            v[12] += ti == 1 ? Y00 : 0.f;
            v[24] += ti == 2 ? Y00 : 0.f;
        }
        int l = (m == 0) ? 0 : (m < 4 ? 1 : 2);
        const float* Al = A + l * 1296;
        #pragma unroll
        for (int an = 0; an < 36; ++an) {
            float s = 0.0f;
            #pragma unroll
            for (int b = 0; b < 36; ++b)
                s = fmaf(Al[an * 36 + b], v[b], s);
            dot = fmaf(v[an], s, dot);
        }
    }
    #pragma unroll
    for (int off = 32; off > 0; off >>= 1) dot += __shfl_down(dot, off, 64);
    if (lane == 0) sred[m] = dot;
    __syncthreads();
    if (threadIdx.x == 0) {
        float s = 0.f;
        #pragma unroll
        for (int k = 0; k < 9; ++k) s += sred[k];
        atomicAdd(out, s);
    }
}

extern "C" void kernel_launch(void* const* d_in, const int* in_sizes, int n_in,
                              void* d_out, int out_size, void* d_ws, size_t ws_size,
                              hipStream_t stream) {
    const float* pos   = (const float*)d_in[0];
    const float* w     = (const float*)d_in[1];
    const float* bias  = (const float*)d_in[2];
    const int*   types = (const int*)d_in[3];
    const int*   pairs = (const int*)d_in[4];
    float* out = (float*)d_out;

    int N = in_sizes[0] / 3;
    int E = in_sizes[4] / 2;

    char* ws = (char*)d_ws;
    size_t off = 0;
    float* A = (float*)(ws + off);            off += 16384;
    int* cnt = (int*)(ws + off);              off += ((size_t)N * 4 + 255) & ~(size_t)255;
    float4* posT = (float4*)(ws + off);       off += ((size_t)N * 16 + 255) & ~(size_t)255;
    int* bucket = (int*)(ws + off);           off += ((size_t)N * BCAP * 4 + 255) & ~(size_t)255;
    __hip_bfloat16* c2 = (__hip_bfloat16*)(ws + off);

    int pblocks = (N + 255) / 256;
    prep_kernel<<<pblocks, 256, 0, stream>>>(w, bias, pos, types, A, posT, cnt, out, N);

    int eblocks = (E + 255) / 256;
    build_kernel<<<eblocks, 256, 0, stream>>>((const int2*)pairs, posT, cnt, bucket, E);

    int ablocks = ((size_t)N * 64 + 255) / 256;
    accum_kernel<<<ablocks, 256, 0, stream>>>(posT, cnt, bucket, c2, N);

    int qblocks = (N + 63) / 64;
    quad_kernel<<<qblocks, 576, 0, stream>>>(c2, types, A, out, N);
}

// Round 6
// 131.611 us; speedup vs baseline: 4.2198x; 1.0734x over previous
//
#include <hip/hip_runtime.h>
#include <hip/hip_bf16.h>

// out = bias + sum_i sum_m quadratic forms (K_m folded into quad stage).
// accum stores UNSCALED c': c'[slot] = sum_edges poly_m(d)*r^(n-k)*gauss*fc
// c2 layout: c2[atom][slot], slot = m*36 + a*12 + n  (bf16, 324/atom)

#define NT 3
#define CPA 324
#define A_ELEMS 3888
#define BCAP 64

typedef __attribute__((ext_vector_type(4))) unsigned short ushort4v;

#if __has_builtin(__builtin_amdgcn_exp2f)
__device__ __forceinline__ float exp2_fast(float x) { return __builtin_amdgcn_exp2f(x); }
#else
__device__ __forceinline__ float exp2_fast(float x) { return __expf(x * 0.6931471805599453f); }
#endif

__global__ void prep_kernel(const float* __restrict__ w,
                            const float* __restrict__ bias,
                            const float* __restrict__ pos,
                            const int* __restrict__ types,
                            float* __restrict__ A,
                            float4* __restrict__ posT,
                            int* __restrict__ cnt,
                            float* __restrict__ out, int N) {
    int t = blockIdx.x * blockDim.x + threadIdx.x;
    if (t == 0) out[0] = bias[0];
    if (t < A_ELEMS) {
        int l   = t / 1296;
        int rem = t - l * 1296;
        int an  = rem / 36;
        int bk  = rem - an * 36;
        int a = an / 12, n = an - (an / 12) * 12;
        int b = bk / 12, k = bk - (bk / 12) * 12;
        float inv = (l == 0) ? 1.0f : (l == 1 ? 0.57735026918962576f
                                              : 0.44721359549995794f);
        A[t] = w[a * 1296 + n * 108 + b * 36 + k * 3 + l] * inv;
    }
    if (t < N) {
        float4 p;
        p.x = pos[3 * t + 0];
        p.y = pos[3 * t + 1];
        p.z = pos[3 * t + 2];
        p.w = __int_as_float(types[t]);
        posT[t] = p;
        cnt[t] = 0;
    }
}

// Single filtering pass into fixed-capacity buckets.
__global__ void build_kernel(const int2* __restrict__ pairs,
                             const float4* __restrict__ posT,
                             int* __restrict__ cnt,
                             int* __restrict__ bucket, int E) {
    int e = blockIdx.x * blockDim.x + threadIdx.x;
    if (e >= E) return;
    int2 pr = pairs[e];
    float4 pi = posT[pr.x], pj = posT[pr.y];
    float dx = pj.x - pi.x, dy = pj.y - pi.y, dz = pj.z - pi.z;
    float r2 = dx * dx + dy * dy + dz * dz;
    if (r2 < 12.96f) {
        int p = atomicAdd(&cnt[pr.x], 1);
        if (p < BCAP) bucket[(pr.x << 6) + p] = pr.y;
    }
}

// Per-slot loop-invariant parameters (d-space polynomial coefficients).
// radial: exp2(fnp*log2(r2) + qc2*r2 + lf), lf = log2(cutoff taper)
struct Slot {
    float fnp, qc2;
    float cxa, cya, cza, cca;            // pa = cxa*dx+cya*dy+cza*dz+cca
    float cxb, cyb, czb, ccb;            // pb
    float cc2;                           // t = pa*pb + cc2*r2
};

__device__ __forceinline__ void slot_init(int m, int n, Slot& s) {
    float fn = (float)n;
    float sg = 0.3f * fmaxf(sqrtf(fn), 1.0f);
    s.qc2 = -0.5f / (sg * sg) * 1.4426950408889634f;   // base-2
    int k = (m == 0) ? 0 : (m < 4 ? 1 : 2);
    s.fnp = 0.5f * (fn - (float)k);
    s.cxa = (m == 3 || m == 4 || m == 7 || m == 8) ? 1.f : 0.f;
    s.cya = (m == 1 || m == 5) ? 1.f : (m == 8 ? -1.f : 0.f);
    s.cza = (m == 2 || m == 6) ? 1.f : 0.f;
    s.cca = (m == 0) ? 1.f : 0.f;
    s.cxb = (m == 8) ? 1.f : 0.f;
    s.cyb = (m == 4 || m == 8) ? 1.f : 0.f;
    s.czb = (m == 5 || m == 6 || m == 7) ? 1.f : 0.f;
    s.ccb = (m <= 3) ? 1.f : 0.f;
    s.cc2 = (m == 6) ? -0.33333333333333333f : 0.f;
}

// One wave per atom. Prologue: lane e gathers edge e's neighbor (1 vector
// load), computes its geometry wave-parallel. Edge loop: broadcast 7 regs
// via v_readlane (no memory ops, no waitcnt) + ~33 VALU per edge.
__global__ void __launch_bounds__(256)
accum_kernel(const float4* __restrict__ posT,
             const int* __restrict__ cnt,
             const int* __restrict__ bucket,
             __hip_bfloat16* __restrict__ c2, int N) {
    int wid = (blockIdx.x * blockDim.x + threadIdx.x) >> 6;
    int lane = threadIdx.x & 63;
    if (wid >= N) return;
    int i = wid;

    float4 pi = posT[i];
    int deg = cnt[i];
    deg = deg > BCAP ? BCAP : deg;

    int jv = bucket[(i << 6) + lane];         // whole bucket row, one load
    int jsafe = (lane < deg) ? jv : i;        // guard stale bucket slots
    float4 pj = posT[jsafe];                  // per-lane vector gather

    // per-lane edge geometry (lane index == edge index)
    float dxl = pj.x - pi.x, dyl = pj.y - pi.y, dzl = pj.z - pi.z;
    float ul  = fmaf(dzl, dzl, fmaf(dyl, dyl, fmaf(dxl, dxl, 1e-12f)));
    float wl  = __log2f(ul);
    float lfl = 0.0f;
    if (ul >= 10.89f) {                       // r >= 3.3: fold taper into exp
        float r = sqrtf(ul);
        float fcv = 0.5f + 0.5f * __cosf(10.471975511965978f * (r - 3.3f));
        lfl = __log2f(fcv);                   // -inf if fcv==0 -> rad=0, OK
    }
    int tjl = __float_as_int(pj.w);

    int n0 = lane % 12, m0 = lane / 12;
    int idx1 = lane + 64;
    bool has1 = idx1 < 108;
    int i1 = has1 ? idx1 : 0;
    int n1 = i1 % 12, m1 = i1 / 12;

    Slot s0, s1;
    slot_init(m0, n0, s0);
    slot_init(m1, n1, s1);

    float a00 = 0.f, a01 = 0.f, a02 = 0.f;
    float a10 = 0.f, a11 = 0.f, a12 = 0.f;

    for (int e = 0; e < deg; ++e) {
        float sdx = __int_as_float(__builtin_amdgcn_readlane(__float_as_int(dxl), e));
        float sdy = __int_as_float(__builtin_amdgcn_readlane(__float_as_int(dyl), e));
        float sdz = __int_as_float(__builtin_amdgcn_readlane(__float_as_int(dzl), e));
        float su  = __int_as_float(__builtin_amdgcn_readlane(__float_as_int(ul),  e));
        float sw  = __int_as_float(__builtin_amdgcn_readlane(__float_as_int(wl),  e));
        float slf = __int_as_float(__builtin_amdgcn_readlane(__float_as_int(lfl), e));
        int   stj = __builtin_amdgcn_readlane(tjl, e);

        float rad0 = exp2_fast(fmaf(s0.fnp, sw, fmaf(s0.qc2, su, slf)));
        float rad1 = exp2_fast(fmaf(s1.fnp, sw, fmaf(s1.qc2, su, slf)));

        float pa0 = fmaf(s0.cxa, sdx, fmaf(s0.cya, sdy, fmaf(s0.cza, sdz, s0.cca)));
        float pb0 = fmaf(s0.cxb, sdx, fmaf(s0.cyb, sdy, fmaf(s0.czb, sdz, s0.ccb)));
        float v0  = rad0 * fmaf(pa0, pb0, s0.cc2 * su);
        float pa1 = fmaf(s1.cxa, sdx, fmaf(s1.cya, sdy, fmaf(s1.cza, sdz, s1.cca)));
        float pb1 = fmaf(s1.cxb, sdx, fmaf(s1.cyb, sdy, fmaf(s1.czb, sdz, s1.ccb)));
        float v1  = rad1 * fmaf(pa1, pb1, s1.cc2 * su);

        if (stj == 0)      { a00 += v0; a10 += v1; }
        else if (stj == 1) { a01 += v0; a11 += v1; }
        else               { a02 += v0; a12 += v1; }
    }

    __hip_bfloat16* cb = c2 + (size_t)i * CPA;
    cb[m0 * 36 + 0 * 12 + n0] = __float2bfloat16(a00);
    cb[m0 * 36 + 1 * 12 + n0] = __float2bfloat16(a01);
    cb[m0 * 36 + 2 * 12 + n0] = __float2bfloat16(a02);
    if (has1) {
        cb[m1 * 36 + 0 * 12 + n1] = __float2bfloat16(a10);
        cb[m1 * 36 + 1 * 12 + n1] = __float2bfloat16(a11);
        cb[m1 * 36 + 2 * 12 + n1] = __float2bfloat16(a12);
    }
}

// Wave = (64 atoms, one m). Rescale v by K_m, add Y00 self-term, v^T A_l v.
__global__ void __launch_bounds__(576)
quad_kernel(const __hip_bfloat16* __restrict__ c2,
            const int* __restrict__ types,
            const float* __restrict__ A,
            float* __restrict__ out, int N) {
    __shared__ float sred[9];
    int m = __builtin_amdgcn_readfirstlane(threadIdx.x >> 6);
    int lane = threadIdx.x & 63;
    int i = blockIdx.x * 64 + lane;
    float dot = 0.0f;
    if (i < N) {
        float Km = m == 0 ? 0.28209479177387814f
                 : (m < 4 ? 0.4886025119029199f
                 : (m == 6 ? 0.94617469575756f
                 : (m == 8 ? 0.5462742152960396f : 1.0925484305920792f)));
        const ushort4v* cb4 =
            (const ushort4v*)(c2 + (size_t)i * CPA + m * 36);
        float v[36];
        #pragma unroll
        for (int q = 0; q < 9; ++q) {
            ushort4v u = cb4[q];
            #pragma unroll
            for (int r = 0; r < 4; ++r)
                v[q * 4 + r] = __uint_as_float(((unsigned)u[r]) << 16) * Km;
        }
        if (m == 0) {
            int ti = types[i];
            const float Y00 = 0.28209479177387814f;
            v[0]  += ti == 0 ? Y00 : 0.f;
            v[12] += ti == 1 ? Y00 : 0.f;
            v[24] += ti == 2 ? Y00 : 0.f;
        }
        int l = (m == 0) ? 0 : (m < 4 ? 1 : 2);
        const float* Al = A + l * 1296;
        #pragma unroll
        for (int an = 0; an < 36; ++an) {
            float s = 0.0f;
            #pragma unroll
            for (int b = 0; b < 36; ++b)
                s = fmaf(Al[an * 36 + b], v[b], s);
            dot = fmaf(v[an], s, dot);
        }
    }
    #pragma unroll
    for (int off = 32; off > 0; off >>= 1) dot += __shfl_down(dot, off, 64);
    if (lane == 0) sred[m] = dot;
    __syncthreads();
    if (threadIdx.x == 0) {
        float s = 0.f;
        #pragma unroll
        for (int k = 0; k < 9; ++k) s += sred[k];
        atomicAdd(out, s);
    }
}

extern "C" void kernel_launch(void* const* d_in, const int* in_sizes, int n_in,
                              void* d_out, int out_size, void* d_ws, size_t ws_size,
                              hipStream_t stream) {
    const float* pos   = (const float*)d_in[0];
    const float* w     = (const float*)d_in[1];
    const float* bias  = (const float*)d_in[2];
    const int*   types = (const int*)d_in[3];
    const int*   pairs = (const int*)d_in[4];
    float* out = (float*)d_out;

    int N = in_sizes[0] / 3;
    int E = in_sizes[4] / 2;

    char* ws = (char*)d_ws;
    size_t off = 0;
    float* A = (float*)(ws + off);            off += 16384;
    int* cnt = (int*)(ws + off);              off += ((size_t)N * 4 + 255) & ~(size_t)255;
    float4* posT = (float4*)(ws + off);       off += ((size_t)N * 16 + 255) & ~(size_t)255;
    int* bucket = (int*)(ws + off);           off += ((size_t)N * BCAP * 4 + 255) & ~(size_t)255;
    __hip_bfloat16* c2 = (__hip_bfloat16*)(ws + off);

    int pblocks = (N + 255) / 256;
    prep_kernel<<<pblocks, 256, 0, stream>>>(w, bias, pos, types, A, posT, cnt, out, N);

    int eblocks = (E + 255) / 256;
    build_kernel<<<eblocks, 256, 0, stream>>>((const int2*)pairs, posT, cnt, bucket, E);

    int ablocks = ((size_t)N * 64 + 255) / 256;
    accum_kernel<<<ablocks, 256, 0, stream>>>(posT, cnt, bucket, c2, N);

    int qblocks = (N + 63) / 64;
    quad_kernel<<<qblocks, 576, 0, stream>>>(c2, types, A, out, N);
}

// Round 7
// 123.585 us; speedup vs baseline: 4.4939x; 1.0649x over previous
//
#include <hip/hip_runtime.h>
#include <hip/hip_bf16.h>

// out = bias + sum_i sum_m quadratic forms (K_m folded into quad stage).
// accum stores UNSCALED c': c'[slot] = sum_edges poly_m(d)*r^(n-k)*gauss*fc
// c2 layout: c2[atom][slot], slot = m*36 + a*12 + n  (bf16, 324/atom)

#define NT 3
#define CPA 324
#define A_ELEMS 3888
#define BCAP 64

typedef __attribute__((ext_vector_type(4))) unsigned short ushort4v;

#if __has_builtin(__builtin_amdgcn_exp2f)
__device__ __forceinline__ float exp2_fast(float x) { return __builtin_amdgcn_exp2f(x); }
#else
__device__ __forceinline__ float exp2_fast(float x) { return __expf(x * 0.6931471805599453f); }
#endif

__device__ __forceinline__ float bcast(float v, int e) {
    return __int_as_float(__builtin_amdgcn_readlane(__float_as_int(v), e));
}

__global__ void prep_kernel(const float* __restrict__ w,
                            const float* __restrict__ bias,
                            const float* __restrict__ pos,
                            const int* __restrict__ types,
                            float* __restrict__ A,
                            float4* __restrict__ posT,
                            int* __restrict__ cnt,
                            float* __restrict__ out, int N) {
    int t = blockIdx.x * blockDim.x + threadIdx.x;
    if (t == 0) out[0] = bias[0];
    if (t < A_ELEMS) {
        int l   = t / 1296;
        int rem = t - l * 1296;
        int an  = rem / 36;
        int bk  = rem - an * 36;
        int a = an / 12, n = an - (an / 12) * 12;
        int b = bk / 12, k = bk - (bk / 12) * 12;
        float inv = (l == 0) ? 1.0f : (l == 1 ? 0.57735026918962576f
                                              : 0.44721359549995794f);
        A[t] = w[a * 1296 + n * 108 + b * 36 + k * 3 + l] * inv;
    }
    if (t < N) {
        float4 p;
        p.x = pos[3 * t + 0];
        p.y = pos[3 * t + 1];
        p.z = pos[3 * t + 2];
        p.w = __int_as_float(types[t]);
        posT[t] = p;
        cnt[t] = 0;
    }
}

// Single filtering pass into fixed-capacity buckets.
__global__ void build_kernel(const int2* __restrict__ pairs,
                             const float4* __restrict__ posT,
                             int* __restrict__ cnt,
                             int* __restrict__ bucket, int E) {
    int e = blockIdx.x * blockDim.x + threadIdx.x;
    if (e >= E) return;
    int2 pr = pairs[e];
    float4 pi = posT[pr.x], pj = posT[pr.y];
    float dx = pj.x - pi.x, dy = pj.y - pi.y, dz = pj.z - pi.z;
    float r2 = dx * dx + dy * dy + dz * dz;
    if (r2 < 12.96f) {
        int p = atomicAdd(&cnt[pr.x], 1);
        if (p < BCAP) bucket[(pr.x << 6) + p] = pr.y;
    }
}

// Per-slot loop-invariant parameters (d-space polynomial coefficients).
// radial: exp2(fnp*log2(r2) + qc2*r2 + lf), lf = log2(cutoff taper)
struct Slot {
    float fnp, qc2;
    float cxa, cya, cza, cca;            // pa = cxa*dx+cya*dy+cza*dz+cca
    float cxb, cyb, czb, ccb;            // pb
    float cc2;                           // t = pa*pb + cc2*r2
};

__device__ __forceinline__ void slot_init(int m, int n, Slot& s) {
    float fn = (float)n;
    float sg = 0.3f * fmaxf(sqrtf(fn), 1.0f);
    s.qc2 = -0.5f / (sg * sg) * 1.4426950408889634f;   // base-2
    int k = (m == 0) ? 0 : (m < 4 ? 1 : 2);
    s.fnp = 0.5f * (fn - (float)k);
    s.cxa = (m == 3 || m == 4 || m == 7 || m == 8) ? 1.f : 0.f;
    s.cya = (m == 1 || m == 5) ? 1.f : (m == 8 ? -1.f : 0.f);
    s.cza = (m == 2 || m == 6) ? 1.f : 0.f;
    s.cca = (m == 0) ? 1.f : 0.f;
    s.cxb = (m == 8) ? 1.f : 0.f;
    s.cyb = (m == 4 || m == 8) ? 1.f : 0.f;
    s.czb = (m == 5 || m == 6 || m == 7) ? 1.f : 0.f;
    s.ccb = (m <= 3) ? 1.f : 0.f;
    s.cc2 = (m == 6) ? -0.33333333333333333f : 0.f;
}

// One wave per atom. Prologue: lane e gathers edge e's neighbor and computes
// its geometry wave-parallel. Edge loop is SCALAR (deg via readfirstlane):
// readlane broadcasts + ~33 VALU per edge, unrolled x2 to overlap exp2 chains.
__global__ void __launch_bounds__(256)
accum_kernel(const float4* __restrict__ posT,
             const int* __restrict__ cnt,
             const int* __restrict__ bucket,
             __hip_bfloat16* __restrict__ c2, int N) {
    int wid = (blockIdx.x * blockDim.x + threadIdx.x) >> 6;
    int lane = threadIdx.x & 63;
    if (wid >= N) return;
    int i = wid;

    float4 pi = posT[i];
    int degv = cnt[i];
    degv = degv > BCAP ? BCAP : degv;
    int deg = __builtin_amdgcn_readfirstlane(degv);   // scalar loop bound

    int jv = bucket[(i << 6) + lane];         // whole bucket row, one load
    int jsafe = (lane < deg) ? jv : i;        // guard stale bucket slots
    float4 pj = posT[jsafe];                  // per-lane vector gather

    // per-lane edge geometry (lane index == edge index)
    float dxl = pj.x - pi.x, dyl = pj.y - pi.y, dzl = pj.z - pi.z;
    float ul  = fmaf(dzl, dzl, fmaf(dyl, dyl, fmaf(dxl, dxl, 1e-12f)));
    float wl  = __log2f(ul);
    float lfl = 0.0f;
    if (ul >= 10.89f) {                       // r >= 3.3: fold taper into exp
        float r = sqrtf(ul);
        float fcv = 0.5f + 0.5f * __cosf(10.471975511965978f * (r - 3.3f));
        lfl = __log2f(fcv);                   // -inf if fcv==0 -> rad=0, OK
    }
    int tjl = __float_as_int(pj.w);

    int n0 = lane % 12, m0 = lane / 12;
    int idx1 = lane + 64;
    bool has1 = idx1 < 108;
    int i1 = has1 ? idx1 : 0;
    int n1 = i1 % 12, m1 = i1 / 12;

    Slot s0, s1;
    slot_init(m0, n0, s0);
    slot_init(m1, n1, s1);

    float a00 = 0.f, a01 = 0.f, a02 = 0.f;
    float a10 = 0.f, a11 = 0.f, a12 = 0.f;

    #define EDGE_BODY(E_IDX)                                                     \
    {                                                                            \
        int   ee  = (E_IDX);                                                     \
        float sdx = bcast(dxl, ee);                                              \
        float sdy = bcast(dyl, ee);                                              \
        float sdz = bcast(dzl, ee);                                              \
        float su  = bcast(ul,  ee);                                              \
        float sw  = bcast(wl,  ee);                                              \
        float slf = bcast(lfl, ee);                                              \
        int   stj = __builtin_amdgcn_readlane(tjl, ee);                          \
        float rad0 = exp2_fast(fmaf(s0.fnp, sw, fmaf(s0.qc2, su, slf)));         \
        float rad1 = exp2_fast(fmaf(s1.fnp, sw, fmaf(s1.qc2, su, slf)));         \
        float pa0 = fmaf(s0.cxa, sdx, fmaf(s0.cya, sdy, fmaf(s0.cza, sdz, s0.cca))); \
        float pb0 = fmaf(s0.cxb, sdx, fmaf(s0.cyb, sdy, fmaf(s0.czb, sdz, s0.ccb))); \
        float v0  = rad0 * fmaf(pa0, pb0, s0.cc2 * su);                          \
        float pa1 = fmaf(s1.cxa, sdx, fmaf(s1.cya, sdy, fmaf(s1.cza, sdz, s1.cca))); \
        float pb1 = fmaf(s1.cxb, sdx, fmaf(s1.cyb, sdy, fmaf(s1.czb, sdz, s1.ccb))); \
        float v1  = rad1 * fmaf(pa1, pb1, s1.cc2 * su);                          \
        if (stj == 0)      { a00 += v0; a10 += v1; }                             \
        else if (stj == 1) { a01 += v0; a11 += v1; }                             \
        else               { a02 += v0; a12 += v1; }                             \
    }

    int e = 0;
    for (; e + 2 <= deg; e += 2) {
        EDGE_BODY(e);
        EDGE_BODY(e + 1);
    }
    if (e < deg) EDGE_BODY(e);
    #undef EDGE_BODY

    __hip_bfloat16* cb = c2 + (size_t)i * CPA;
    cb[m0 * 36 + 0 * 12 + n0] = __float2bfloat16(a00);
    cb[m0 * 36 + 1 * 12 + n0] = __float2bfloat16(a01);
    cb[m0 * 36 + 2 * 12 + n0] = __float2bfloat16(a02);
    if (has1) {
        cb[m1 * 36 + 0 * 12 + n1] = __float2bfloat16(a10);
        cb[m1 * 36 + 1 * 12 + n1] = __float2bfloat16(a11);
        cb[m1 * 36 + 2 * 12 + n1] = __float2bfloat16(a12);
    }
}

// Wave = (64 atoms, one m). Rescale v by K_m, add Y00 self-term, v^T A_l v.
__global__ void __launch_bounds__(576)
quad_kernel(const __hip_bfloat16* __restrict__ c2,
            const int* __restrict__ types,
            const float* __restrict__ A,
            float* __restrict__ out, int N) {
    __shared__ float sred[9];
    int m = __builtin_amdgcn_readfirstlane(threadIdx.x >> 6);
    int lane = threadIdx.x & 63;
    int i = blockIdx.x * 64 + lane;
    float dot = 0.0f;
    if (i < N) {
        float Km = m == 0 ? 0.28209479177387814f
                 : (m < 4 ? 0.4886025119029199f
                 : (m == 6 ? 0.94617469575756f
                 : (m == 8 ? 0.5462742152960396f : 1.0925484305920792f)));
        const ushort4v* cb4 =
            (const ushort4v*)(c2 + (size_t)i * CPA + m * 36);
        float v[36];
        #pragma unroll
        for (int q = 0; q < 9; ++q) {
            ushort4v u = cb4[q];
            #pragma unroll
            for (int r = 0; r < 4; ++r)
                v[q * 4 + r] = __uint_as_float(((unsigned)u[r]) << 16) * Km;
        }
        if (m == 0) {
            int ti = types[i];
            const float Y00 = 0.28209479177387814f;
            v[0]  += ti == 0 ? Y00 : 0.f;
            v[12] += ti == 1 ? Y00 : 0.f;
            v[24] += ti == 2 ? Y00 : 0.f;
        }
        int l = (m == 0) ? 0 : (m < 4 ? 1 : 2);
        const float* Al = A + l * 1296;
        #pragma unroll
        for (int an = 0; an < 36; ++an) {
            float s = 0.0f;
            #pragma unroll
            for (int b = 0; b < 36; ++b)
                s = fmaf(Al[an * 36 + b], v[b], s);
            dot = fmaf(v[an], s, dot);
        }
    }
    #pragma unroll
    for (int off = 32; off > 0; off >>= 1) dot += __shfl_down(dot, off, 64);
    if (lane == 0) sred[m] = dot;
    __syncthreads();
    if (threadIdx.x == 0) {
        float s = 0.f;
        #pragma unroll
        for (int k = 0; k < 9; ++k) s += sred[k];
        atomicAdd(out, s);
    }
}

extern "C" void kernel_launch(void* const* d_in, const int* in_sizes, int n_in,
                              void* d_out, int out_size, void* d_ws, size_t ws_size,
                              hipStream_t stream) {
    const float* pos   = (const float*)d_in[0];
    const float* w     = (const float*)d_in[1];
    const float* bias  = (const float*)d_in[2];
    const int*   types = (const int*)d_in[3];
    const int*   pairs = (const int*)d_in[4];
    float* out = (float*)d_out;

    int N = in_sizes[0] / 3;
    int E = in_sizes[4] / 2;

    char* ws = (char*)d_ws;
    size_t off = 0;
    float* A = (float*)(ws + off);            off += 16384;
    int* cnt = (int*)(ws + off);              off += ((size_t)N * 4 + 255) & ~(size_t)255;
    float4* posT = (float4*)(ws + off);       off += ((size_t)N * 16 + 255) & ~(size_t)255;
    int* bucket = (int*)(ws + off);           off += ((size_t)N * BCAP * 4 + 255) & ~(size_t)255;
    __hip_bfloat16* c2 = (__hip_bfloat16*)(ws + off);

    int pblocks = (N + 255) / 256;
    prep_kernel<<<pblocks, 256, 0, stream>>>(w, bias, pos, types, A, posT, cnt, out, N);

    int eblocks = (E + 255) / 256;
    build_kernel<<<eblocks, 256, 0, stream>>>((const int2*)pairs, posT, cnt, bucket, E);

    int ablocks = ((size_t)N * 64 + 255) / 256;
    accum_kernel<<<ablocks, 256, 0, stream>>>(posT, cnt, bucket, c2, N);

    int qblocks = (N + 63) / 64;
    quad_kernel<<<qblocks, 576, 0, stream>>>(c2, types, A, out, N);
}

// Round 8
// 110.612 us; speedup vs baseline: 5.0209x; 1.1173x over previous
//
#include <hip/hip_runtime.h>
#include <hip/hip_bf16.h>

// out = bias + sum_i sum_m quadratic forms (K_m folded into quad stage).
// accum stores UNSCALED c': c'[slot] = sum_edges poly_m(d)*r^(n-k)*gauss*fc
// c2 layout: c2[atom][slot], slot = m*36 + a*12 + n  (bf16, 324/atom)

#define NT 3
#define CPA 324
#define A_ELEMS 3888
#define BCAP 64
#define WPB 4      // waves per block in accum

typedef __attribute__((ext_vector_type(4))) unsigned short ushort4v;

#if __has_builtin(__builtin_amdgcn_exp2f)
__device__ __forceinline__ float exp2_fast(float x) { return __builtin_amdgcn_exp2f(x); }
#else
__device__ __forceinline__ float exp2_fast(float x) { return __expf(x * 0.6931471805599453f); }
#endif

__global__ void prep_kernel(const float* __restrict__ w,
                            const float* __restrict__ bias,
                            const float* __restrict__ pos,
                            const int* __restrict__ types,
                            float* __restrict__ A,
                            float4* __restrict__ posT,
                            int* __restrict__ cnt,
                            float* __restrict__ out, int N) {
    int t = blockIdx.x * blockDim.x + threadIdx.x;
    if (t == 0) out[0] = bias[0];
    if (t < A_ELEMS) {
        int l   = t / 1296;
        int rem = t - l * 1296;
        int an  = rem / 36;
        int bk  = rem - an * 36;
        int a = an / 12, n = an - (an / 12) * 12;
        int b = bk / 12, k = bk - (bk / 12) * 12;
        float inv = (l == 0) ? 1.0f : (l == 1 ? 0.57735026918962576f
                                              : 0.44721359549995794f);
        A[t] = w[a * 1296 + n * 108 + b * 36 + k * 3 + l] * inv;
    }
    if (t < N) {
        float4 p;
        p.x = pos[3 * t + 0];
        p.y = pos[3 * t + 1];
        p.z = pos[3 * t + 2];
        p.w = __int_as_float(types[t]);
        posT[t] = p;
        cnt[t] = 0;
    }
}

// Filtering pass into fixed-capacity buckets; 2 edges per thread (int4 load).
__global__ void build_kernel(const int* __restrict__ pairs,
                             const float4* __restrict__ posT,
                             int* __restrict__ cnt,
                             int* __restrict__ bucket, int E) {
    int t = blockIdx.x * blockDim.x + threadIdx.x;
    int e0 = t << 1;
    if (e0 >= E) return;
    int pi0, pj0, pi1 = 0, pj1 = 0;
    bool two = (e0 + 1) < E;
    if (two) {
        int4 p4 = ((const int4*)pairs)[t];
        pi0 = p4.x; pj0 = p4.y; pi1 = p4.z; pj1 = p4.w;
    } else {
        pi0 = pairs[2 * e0]; pj0 = pairs[2 * e0 + 1];
    }
    {
        float4 a = posT[pi0], b = posT[pj0];
        float dx = b.x - a.x, dy = b.y - a.y, dz = b.z - a.z;
        float r2 = dx * dx + dy * dy + dz * dz;
        if (r2 < 12.96f) {
            int p = atomicAdd(&cnt[pi0], 1);
            if (p < BCAP) bucket[(pi0 << 6) + p] = pj0;
        }
    }
    if (two) {
        float4 a = posT[pi1], b = posT[pj1];
        float dx = b.x - a.x, dy = b.y - a.y, dz = b.z - a.z;
        float r2 = dx * dx + dy * dy + dz * dz;
        if (r2 < 12.96f) {
            int p = atomicAdd(&cnt[pi1], 1);
            if (p < BCAP) bucket[(pi1 << 6) + p] = pj1;
        }
    }
}

// Per-slot loop-invariant parameters (d-space polynomial coefficients).
// radial: exp2(fnp*log2(r2) + qc2*r2 + lf), lf = log2(cutoff taper)
struct Slot {
    float fnp, qc2;
    float cxa, cya, cza, cca;            // pa = cxa*dx+cya*dy+cza*dz+cca
    float cxb, cyb, czb, ccb;            // pb
    float cc2;                           // t = pa*pb + cc2*r2
};

__device__ __forceinline__ void slot_init(int m, int n, Slot& s) {
    float fn = (float)n;
    float sg = 0.3f * fmaxf(sqrtf(fn), 1.0f);
    s.qc2 = -0.5f / (sg * sg) * 1.4426950408889634f;   // base-2
    int k = (m == 0) ? 0 : (m < 4 ? 1 : 2);
    s.fnp = 0.5f * (fn - (float)k);
    s.cxa = (m == 3 || m == 4 || m == 7 || m == 8) ? 1.f : 0.f;
    s.cya = (m == 1 || m == 5) ? 1.f : (m == 8 ? -1.f : 0.f);
    s.cza = (m == 2 || m == 6) ? 1.f : 0.f;
    s.cca = (m == 0) ? 1.f : 0.f;
    s.cxb = (m == 8) ? 1.f : 0.f;
    s.cyb = (m == 4 || m == 8) ? 1.f : 0.f;
    s.czb = (m == 5 || m == 6 || m == 7) ? 1.f : 0.f;
    s.ccb = (m <= 3) ? 1.f : 0.f;
    s.cc2 = (m == 6) ? -0.33333333333333333f : 0.f;
}

// One wave per atom. Prologue: lane e gathers edge e's neighbor, computes its
// geometry, writes an 8-float record to LDS. Edge loop: 2 uniform-address
// ds_read_b128 (broadcast, LDS pipe) + ~25 VALU + 2 exp2 per edge. No
// readlanes, no memory latency in the loop's VALU path.
__global__ void __launch_bounds__(256)
accum_kernel(const float4* __restrict__ posT,
             const int* __restrict__ cnt,
             const int* __restrict__ bucket,
             __hip_bfloat16* __restrict__ c2, int N) {
    __shared__ float sE[WPB][64][8];
    int wid = (blockIdx.x * blockDim.x + threadIdx.x) >> 6;
    int lane = threadIdx.x & 63;
    int wslot = (threadIdx.x >> 6);
    if (wid >= N) return;
    int i = wid;

    float4 pi = posT[i];
    int degv = cnt[i];
    degv = degv > BCAP ? BCAP : degv;
    int deg = __builtin_amdgcn_readfirstlane(degv);   // scalar loop bound

    int jv = bucket[(i << 6) + lane];         // whole bucket row, one load
    int jsafe = (lane < deg) ? jv : i;        // guard stale bucket slots
    float4 pj = posT[jsafe];                  // per-lane vector gather

    // per-lane edge geometry (lane index == edge index)
    float dxl = pj.x - pi.x, dyl = pj.y - pi.y, dzl = pj.z - pi.z;
    float ul  = fmaf(dzl, dzl, fmaf(dyl, dyl, fmaf(dxl, dxl, 1e-12f)));
    float wl  = __log2f(ul);
    float lfl = 0.0f;
    if (ul >= 10.89f) {                       // r >= 3.3: fold taper into exp
        float r = sqrtf(ul);
        float fcv = 0.5f + 0.5f * __cosf(10.471975511965978f * (r - 3.3f));
        lfl = __log2f(fcv);                   // fcv>0 in bucket (r<3.6)
    }

    float4* wr = (float4*)&sE[wslot][lane][0];
    wr[0] = make_float4(dxl, dyl, dzl, ul);
    wr[1] = make_float4(wl, lfl, pj.w, 0.0f);   // pj.w carries type bits
    // wave-coherent LDS: drain writes before cross-lane reads (same wave)
    asm volatile("s_waitcnt lgkmcnt(0)" ::: "memory");

    int n0 = lane % 12, m0 = lane / 12;
    int idx1 = lane + 64;
    bool has1 = idx1 < 108;
    int i1 = has1 ? idx1 : 0;
    int n1 = i1 % 12, m1 = i1 / 12;

    Slot s0, s1;
    slot_init(m0, n0, s0);
    slot_init(m1, n1, s1);

    float a00 = 0.f, a01 = 0.f, a02 = 0.f;
    float a10 = 0.f, a11 = 0.f, a12 = 0.f;

    #define EDGE_BODY(E_IDX)                                                     \
    {                                                                            \
        const float4 g0 = *(const float4*)&sE[wslot][(E_IDX)][0];                \
        const float4 g1 = *(const float4*)&sE[wslot][(E_IDX)][4];                \
        float sdx = g0.x, sdy = g0.y, sdz = g0.z, su = g0.w;                     \
        float sw = g1.x, slf = g1.y;                                             \
        int   stj = __builtin_amdgcn_readfirstlane(__float_as_int(g1.z));        \
        float rad0 = exp2_fast(fmaf(s0.fnp, sw, fmaf(s0.qc2, su, slf)));         \
        float rad1 = exp2_fast(fmaf(s1.fnp, sw, fmaf(s1.qc2, su, slf)));         \
        float pa0 = fmaf(s0.cxa, sdx, fmaf(s0.cya, sdy, fmaf(s0.cza, sdz, s0.cca))); \
        float pb0 = fmaf(s0.cxb, sdx, fmaf(s0.cyb, sdy, fmaf(s0.czb, sdz, s0.ccb))); \
        float v0  = rad0 * fmaf(pa0, pb0, s0.cc2 * su);                          \
        float pa1 = fmaf(s1.cxa, sdx, fmaf(s1.cya, sdy, fmaf(s1.cza, sdz, s1.cca))); \
        float pb1 = fmaf(s1.cxb, sdx, fmaf(s1.cyb, sdy, fmaf(s1.czb, sdz, s1.ccb))); \
        float v1  = rad1 * fmaf(pa1, pb1, s1.cc2 * su);                          \
        if (stj == 0)      { a00 += v0; a10 += v1; }                             \
        else if (stj == 1) { a01 += v0; a11 += v1; }                             \
        else               { a02 += v0; a12 += v1; }                             \
    }

    int e = 0;
    for (; e + 2 <= deg; e += 2) {
        EDGE_BODY(e);
        EDGE_BODY(e + 1);
    }
    if (e < deg) EDGE_BODY(e);
    #undef EDGE_BODY

    __hip_bfloat16* cb = c2 + (size_t)i * CPA;
    cb[m0 * 36 + 0 * 12 + n0] = __float2bfloat16(a00);
    cb[m0 * 36 + 1 * 12 + n0] = __float2bfloat16(a01);
    cb[m0 * 36 + 2 * 12 + n0] = __float2bfloat16(a02);
    if (has1) {
        cb[m1 * 36 + 0 * 12 + n1] = __float2bfloat16(a10);
        cb[m1 * 36 + 1 * 12 + n1] = __float2bfloat16(a11);
        cb[m1 * 36 + 2 * 12 + n1] = __float2bfloat16(a12);
    }
}

// Wave = (64 atoms, one m). Rescale v by K_m, add Y00 self-term, v^T A_l v.
__global__ void __launch_bounds__(576)
quad_kernel(const __hip_bfloat16* __restrict__ c2,
            const int* __restrict__ types,
            const float* __restrict__ A,
            float* __restrict__ out, int N) {
    __shared__ float sred[9];
    int m = __builtin_amdgcn_readfirstlane(threadIdx.x >> 6);
    int lane = threadIdx.x & 63;
    int i = blockIdx.x * 64 + lane;
    float dot = 0.0f;
    if (i < N) {
        float Km = m == 0 ? 0.28209479177387814f
                 : (m < 4 ? 0.4886025119029199f
                 : (m == 6 ? 0.94617469575756f
                 : (m == 8 ? 0.5462742152960396f : 1.0925484305920792f)));
        const ushort4v* cb4 =
            (const ushort4v*)(c2 + (size_t)i * CPA + m * 36);
        float v[36];
        #pragma unroll
        for (int q = 0; q < 9; ++q) {
            ushort4v u = cb4[q];
            #pragma unroll
            for (int r = 0; r < 4; ++r)
                v[q * 4 + r] = __uint_as_float(((unsigned)u[r]) << 16) * Km;
        }
        if (m == 0) {
            int ti = types[i];
            const float Y00 = 0.28209479177387814f;
            v[0]  += ti == 0 ? Y00 : 0.f;
            v[12] += ti == 1 ? Y00 : 0.f;
            v[24] += ti == 2 ? Y00 : 0.f;
        }
        int l = (m == 0) ? 0 : (m < 4 ? 1 : 2);
        const float* Al = A + l * 1296;
        #pragma unroll
        for (int an = 0; an < 36; ++an) {
            float s = 0.0f;
            #pragma unroll
            for (int b = 0; b < 36; ++b)
                s = fmaf(Al[an * 36 + b], v[b], s);
            dot = fmaf(v[an], s, dot);
        }
    }
    #pragma unroll
    for (int off = 32; off > 0; off >>= 1) dot += __shfl_down(dot, off, 64);
    if (lane == 0) sred[m] = dot;
    __syncthreads();
    if (threadIdx.x == 0) {
        float s = 0.f;
        #pragma unroll
        for (int k = 0; k < 9; ++k) s += sred[k];
        atomicAdd(out, s);
    }
}

extern "C" void kernel_launch(void* const* d_in, const int* in_sizes, int n_in,
                              void* d_out, int out_size, void* d_ws, size_t ws_size,
                              hipStream_t stream) {
    const float* pos   = (const float*)d_in[0];
    const float* w     = (const float*)d_in[1];
    const float* bias  = (const float*)d_in[2];
    const int*   types = (const int*)d_in[3];
    const int*   pairs = (const int*)d_in[4];
    float* out = (float*)d_out;

    int N = in_sizes[0] / 3;
    int E = in_sizes[4] / 2;

    char* ws = (char*)d_ws;
    size_t off = 0;
    float* A = (float*)(ws + off);            off += 16384;
    int* cnt = (int*)(ws + off);              off += ((size_t)N * 4 + 255) & ~(size_t)255;
    float4* posT = (float4*)(ws + off);       off += ((size_t)N * 16 + 255) & ~(size_t)255;
    int* bucket = (int*)(ws + off);           off += ((size_t)N * BCAP * 4 + 255) & ~(size_t)255;
    __hip_bfloat16* c2 = (__hip_bfloat16*)(ws + off);

    int pblocks = (N + 255) / 256;
    prep_kernel<<<pblocks, 256, 0, stream>>>(w, bias, pos, types, A, posT, cnt, out, N);

    int ehalf = (E + 1) / 2;
    int eblocks = (ehalf + 255) / 256;
    build_kernel<<<eblocks, 256, 0, stream>>>(pairs, posT, cnt, bucket, E);

    int ablocks = ((size_t)N * 64 + 255) / 256;
    accum_kernel<<<ablocks, 256, 0, stream>>>(posT, cnt, bucket, c2, N);

    int qblocks = (N + 63) / 64;
    quad_kernel<<<qblocks, 576, 0, stream>>>(c2, types, A, out, N);
}

// Round 9
// 108.431 us; speedup vs baseline: 5.1219x; 1.0201x over previous
//
#include <hip/hip_runtime.h>
#include <hip/hip_bf16.h>

// out = bias + sum_i sum_m quadratic forms (K_m folded into quad stage).
// accum stores UNSCALED c': c'[slot] = sum_edges poly_m(d)*r^(n-k)*gauss*fc
// c2 layout: c2[atom][slot], slot = m*36 + a*12 + n  (bf16, 324/atom)

#define NT 3
#define CPA 324
#define A_ELEMS 3888
#define BCAP 64
#define WPB 4      // waves per block in accum

typedef __attribute__((ext_vector_type(4))) unsigned short ushort4v;

#if __has_builtin(__builtin_amdgcn_exp2f)
__device__ __forceinline__ float exp2_fast(float x) { return __builtin_amdgcn_exp2f(x); }
#else
__device__ __forceinline__ float exp2_fast(float x) { return __expf(x * 0.6931471805599453f); }
#endif

__global__ void prep_kernel(const float* __restrict__ w,
                            const float* __restrict__ bias,
                            const float* __restrict__ pos,
                            const int* __restrict__ types,
                            float* __restrict__ A,
                            float4* __restrict__ posT,
                            int* __restrict__ cnt,
                            float* __restrict__ out, int N) {
    int t = blockIdx.x * blockDim.x + threadIdx.x;
    if (t == 0) out[0] = bias[0];
    if (t < A_ELEMS) {
        int l   = t / 1296;
        int rem = t - l * 1296;
        int an  = rem / 36;
        int bk  = rem - an * 36;
        int a = an / 12, n = an - (an / 12) * 12;
        int b = bk / 12, k = bk - (bk / 12) * 12;
        float inv = (l == 0) ? 1.0f : (l == 1 ? 0.57735026918962576f
                                              : 0.44721359549995794f);
        A[t] = w[a * 1296 + n * 108 + b * 36 + k * 3 + l] * inv;
    }
    if (t < N) {
        float4 p;
        p.x = pos[3 * t + 0];
        p.y = pos[3 * t + 1];
        p.z = pos[3 * t + 2];
        p.w = __int_as_float(types[t]);
        posT[t] = p;
        cnt[t] = 0;
    }
}

// Filtering pass into fixed-capacity buckets; 2 edges per thread (int4 load).
__global__ void build_kernel(const int* __restrict__ pairs,
                             const float4* __restrict__ posT,
                             int* __restrict__ cnt,
                             int* __restrict__ bucket, int E) {
    int t = blockIdx.x * blockDim.x + threadIdx.x;
    int e0 = t << 1;
    if (e0 >= E) return;
    int pi0, pj0, pi1 = 0, pj1 = 0;
    bool two = (e0 + 1) < E;
    if (two) {
        int4 p4 = ((const int4*)pairs)[t];
        pi0 = p4.x; pj0 = p4.y; pi1 = p4.z; pj1 = p4.w;
    } else {
        pi0 = pairs[2 * e0]; pj0 = pairs[2 * e0 + 1];
    }
    {
        float4 a = posT[pi0], b = posT[pj0];
        float dx = b.x - a.x, dy = b.y - a.y, dz = b.z - a.z;
        float r2 = dx * dx + dy * dy + dz * dz;
        if (r2 < 12.96f) {
            int p = atomicAdd(&cnt[pi0], 1);
            if (p < BCAP) bucket[(pi0 << 6) + p] = pj0;
        }
    }
    if (two) {
        float4 a = posT[pi1], b = posT[pj1];
        float dx = b.x - a.x, dy = b.y - a.y, dz = b.z - a.z;
        float r2 = dx * dx + dy * dy + dz * dz;
        if (r2 < 12.96f) {
            int p = atomicAdd(&cnt[pi1], 1);
            if (p < BCAP) bucket[(pi1 << 6) + p] = pj1;
        }
    }
}

// Per-slot loop-invariant parameters (d-space polynomial coefficients).
// radial: exp2(fnp*log2(r2) + qc2*r2 + lf), lf = log2(cutoff taper)
struct Slot {
    float fnp, qc2;
    float cxa, cya, cza, cca;            // pa = cxa*dx+cya*dy+cza*dz+cca
    float cxb, cyb, czb, ccb;            // pb
    float cc2;                           // t = pa*pb + cc2*r2
};

__device__ __forceinline__ void slot_init(int m, int n, Slot& s) {
    float fn = (float)n;
    float sg = 0.3f * fmaxf(sqrtf(fn), 1.0f);
    s.qc2 = -0.5f / (sg * sg) * 1.4426950408889634f;   // base-2
    int k = (m == 0) ? 0 : (m < 4 ? 1 : 2);
    s.fnp = 0.5f * (fn - (float)k);
    s.cxa = (m == 3 || m == 4 || m == 7 || m == 8) ? 1.f : 0.f;
    s.cya = (m == 1 || m == 5) ? 1.f : (m == 8 ? -1.f : 0.f);
    s.cza = (m == 2 || m == 6) ? 1.f : 0.f;
    s.cca = (m == 0) ? 1.f : 0.f;
    s.cxb = (m == 8) ? 1.f : 0.f;
    s.cyb = (m == 4 || m == 8) ? 1.f : 0.f;
    s.czb = (m == 5 || m == 6 || m == 7) ? 1.f : 0.f;
    s.ccb = (m <= 3) ? 1.f : 0.f;
    s.cc2 = (m == 6) ? -0.33333333333333333f : 0.f;
}

// One wave per atom. Prologue: lane e gathers its edge, computes geometry,
// TYPE-SORTS the wave's edges via ballots, writes 6-float records to LDS at
// sorted position. Edge loop: 3 scalar-bounded segments with fixed
// accumulator targets -> no per-edge branch, acc folded into fma.
__global__ void __launch_bounds__(256)
accum_kernel(const float4* __restrict__ posT,
             const int* __restrict__ cnt,
             const int* __restrict__ bucket,
             __hip_bfloat16* __restrict__ c2, int N) {
    __shared__ float sE[WPB][64][8];
    int wid = (blockIdx.x * blockDim.x + threadIdx.x) >> 6;
    int lane = threadIdx.x & 63;
    int wslot = (threadIdx.x >> 6);
    if (wid >= N) return;
    int i = wid;

    float4 pi = posT[i];
    int degv = cnt[i];
    degv = degv > BCAP ? BCAP : degv;
    int deg = __builtin_amdgcn_readfirstlane(degv);   // scalar loop bound

    int jv = bucket[(i << 6) + lane];         // whole bucket row, one load
    bool valid = lane < deg;
    int jsafe = valid ? jv : i;               // guard stale bucket slots
    float4 pj = posT[jsafe];                  // per-lane vector gather

    // per-lane edge geometry (lane index == edge index, pre-sort)
    float dxl = pj.x - pi.x, dyl = pj.y - pi.y, dzl = pj.z - pi.z;
    float ul  = fmaf(dzl, dzl, fmaf(dyl, dyl, fmaf(dxl, dxl, 1e-12f)));
    float wl  = __log2f(ul);
    float lfl = 0.0f;
    if (ul >= 10.89f) {                       // r >= 3.3: fold taper into exp
        float r = sqrtf(ul);
        float fcv = 0.5f + 0.5f * __cosf(10.471975511965978f * (r - 3.3f));
        lfl = __log2f(fcv);                   // fcv>0 in bucket (r<3.6)
    }
    int tj = __float_as_int(pj.w);

    // ---- type-sort: dest = segment base + rank within segment ----
    unsigned long long b0 = __ballot(valid && tj == 0);
    unsigned long long b1 = __ballot(valid && tj == 1);
    unsigned long long b2 = __ballot(valid && tj == 2);
    unsigned long long lt = (lane == 63) ? 0xFFFFFFFFFFFFFFFFull >> 1
                                         : ((1ull << lane) - 1ull);
    // note: (1ull<<63)-1 is fine too; the above avoids UB pedantry
    int c0 = __popcll(b0);
    int c1 = __popcll(b1);
    int dest;
    if (!valid) {
        unsigned long long binv = ~(b0 | b1 | b2);
        dest = deg + __popcll(binv & lt);
    } else if (tj == 0) {
        dest = __popcll(b0 & lt);
    } else if (tj == 1) {
        dest = c0 + __popcll(b1 & lt);
    } else {
        dest = c0 + c1 + __popcll(b2 & lt);
    }

    *(float4*)&sE[wslot][dest][0] = make_float4(dxl, dyl, dzl, ul);
    *(float2*)&sE[wslot][dest][4] = make_float2(wl, lfl);
    // wave-coherent LDS: drain writes before cross-lane reads (same wave)
    asm volatile("s_waitcnt lgkmcnt(0)" ::: "memory");

    int e1b = c0 + c1;            // scalar (popc of uniform ballot)

    int n0 = lane % 12, m0 = lane / 12;
    int idx1 = lane + 64;
    bool has1 = idx1 < 108;
    int i1 = has1 ? idx1 : 0;
    int n1 = i1 % 12, m1 = i1 / 12;

    Slot s0, s1;
    slot_init(m0, n0, s0);
    slot_init(m1, n1, s1);

    float a00 = 0.f, a01 = 0.f, a02 = 0.f;
    float a10 = 0.f, a11 = 0.f, a12 = 0.f;

    #define EDGE_BODY(E_IDX, ACC0, ACC1)                                         \
    {                                                                            \
        const float4 g0 = *(const float4*)&sE[wslot][(E_IDX)][0];                \
        const float2 g1 = *(const float2*)&sE[wslot][(E_IDX)][4];                \
        float sdx = g0.x, sdy = g0.y, sdz = g0.z, su = g0.w;                     \
        float sw = g1.x, slf = g1.y;                                             \
        float rad0 = exp2_fast(fmaf(s0.fnp, sw, fmaf(s0.qc2, su, slf)));         \
        float rad1 = exp2_fast(fmaf(s1.fnp, sw, fmaf(s1.qc2, su, slf)));         \
        float pa0 = fmaf(s0.cxa, sdx, fmaf(s0.cya, sdy, fmaf(s0.cza, sdz, s0.cca))); \
        float pb0 = fmaf(s0.cxb, sdx, fmaf(s0.cyb, sdy, fmaf(s0.czb, sdz, s0.ccb))); \
        float q0  = fmaf(pa0, pb0, s0.cc2 * su);                                 \
        ACC0 = fmaf(rad0, q0, ACC0);                                             \
        float pa1 = fmaf(s1.cxa, sdx, fmaf(s1.cya, sdy, fmaf(s1.cza, sdz, s1.cca))); \
        float pb1 = fmaf(s1.cxb, sdx, fmaf(s1.cyb, sdy, fmaf(s1.czb, sdz, s1.ccb))); \
        float q1  = fmaf(pa1, pb1, s1.cc2 * su);                                 \
        ACC1 = fmaf(rad1, q1, ACC1);                                             \
    }

    int e = 0;
    #pragma unroll 2
    for (; e < c0; ++e)  EDGE_BODY(e, a00, a10);
    #pragma unroll 2
    for (; e < e1b; ++e) EDGE_BODY(e, a01, a11);
    #pragma unroll 2
    for (; e < deg; ++e) EDGE_BODY(e, a02, a12);
    #undef EDGE_BODY

    __hip_bfloat16* cb = c2 + (size_t)i * CPA;
    cb[m0 * 36 + 0 * 12 + n0] = __float2bfloat16(a00);
    cb[m0 * 36 + 1 * 12 + n0] = __float2bfloat16(a01);
    cb[m0 * 36 + 2 * 12 + n0] = __float2bfloat16(a02);
    if (has1) {
        cb[m1 * 36 + 0 * 12 + n1] = __float2bfloat16(a10);
        cb[m1 * 36 + 1 * 12 + n1] = __float2bfloat16(a11);
        cb[m1 * 36 + 2 * 12 + n1] = __float2bfloat16(a12);
    }
}

// Wave = (64 atoms, one m). Rescale v by K_m, add Y00 self-term, v^T A_l v.
__global__ void __launch_bounds__(576)
quad_kernel(const __hip_bfloat16* __restrict__ c2,
            const int* __restrict__ types,
            const float* __restrict__ A,
            float* __restrict__ out, int N) {
    __shared__ float sred[9];
    int m = __builtin_amdgcn_readfirstlane(threadIdx.x >> 6);
    int lane = threadIdx.x & 63;
    int i = blockIdx.x * 64 + lane;
    float dot = 0.0f;
    if (i < N) {
        float Km = m == 0 ? 0.28209479177387814f
                 : (m < 4 ? 0.4886025119029199f
                 : (m == 6 ? 0.94617469575756f
                 : (m == 8 ? 0.5462742152960396f : 1.0925484305920792f)));
        const ushort4v* cb4 =
            (const ushort4v*)(c2 + (size_t)i * CPA + m * 36);
        float v[36];
        #pragma unroll
        for (int q = 0; q < 9; ++q) {
            ushort4v u = cb4[q];
            #pragma unroll
            for (int r = 0; r < 4; ++r)
                v[q * 4 + r] = __uint_as_float(((unsigned)u[r]) << 16) * Km;
        }
        if (m == 0) {
            int ti = types[i];
            const float Y00 = 0.28209479177387814f;
            v[0]  += ti == 0 ? Y00 : 0.f;
            v[12] += ti == 1 ? Y00 : 0.f;
            v[24] += ti == 2 ? Y00 : 0.f;
        }
        int l = (m == 0) ? 0 : (m < 4 ? 1 : 2);
        const float* Al = A + l * 1296;
        #pragma unroll
        for (int an = 0; an < 36; ++an) {
            float s = 0.0f;
            #pragma unroll
            for (int b = 0; b < 36; ++b)
                s = fmaf(Al[an * 36 + b], v[b], s);
            dot = fmaf(v[an], s, dot);
        }
    }
    #pragma unroll
    for (int off = 32; off > 0; off >>= 1) dot += __shfl_down(dot, off, 64);
    if (lane == 0) sred[m] = dot;
    __syncthreads();
    if (threadIdx.x == 0) {
        float s = 0.f;
        #pragma unroll
        for (int k = 0; k < 9; ++k) s += sred[k];
        atomicAdd(out, s);
    }
}

extern "C" void kernel_launch(void* const* d_in, const int* in_sizes, int n_in,
                              void* d_out, int out_size, void* d_ws, size_t ws_size,
                              hipStream_t stream) {
    const float* pos   = (const float*)d_in[0];
    const float* w     = (const float*)d_in[1];
    const float* bias  = (const float*)d_in[2];
    const int*   types = (const int*)d_in[3];
    const int*   pairs = (const int*)d_in[4];
    float* out = (float*)d_out;

    int N = in_sizes[0] / 3;
    int E = in_sizes[4] / 2;

    char* ws = (char*)d_ws;
    size_t off = 0;
    float* A = (float*)(ws + off);            off += 16384;
    int* cnt = (int*)(ws + off);              off += ((size_t)N * 4 + 255) & ~(size_t)255;
    float4* posT = (float4*)(ws + off);       off += ((size_t)N * 16 + 255) & ~(size_t)255;
    int* bucket = (int*)(ws + off);           off += ((size_t)N * BCAP * 4 + 255) & ~(size_t)255;
    __hip_bfloat16* c2 = (__hip_bfloat16*)(ws + off);

    int pblocks = (N + 255) / 256;
    prep_kernel<<<pblocks, 256, 0, stream>>>(w, bias, pos, types, A, posT, cnt, out, N);

    int ehalf = (E + 1) / 2;
    int eblocks = (ehalf + 255) / 256;
    build_kernel<<<eblocks, 256, 0, stream>>>(pairs, posT, cnt, bucket, E);

    int ablocks = ((size_t)N * 64 + 255) / 256;
    accum_kernel<<<ablocks, 256, 0, stream>>>(posT, cnt, bucket, c2, N);

    int qblocks = (N + 63) / 64;
    quad_kernel<<<qblocks, 576, 0, stream>>>(c2, types, A, out, N);
}